// Round 1
// baseline (3868.453 us; speedup 1.0000x reference)
//
#include <hip/hip_runtime.h>

#define NHEAD 8
#define DHEAD 16
#define NPAPER 100000
#define NAUTHOR 60000
#define NSUBJ 1000
#define NTOT (NPAPER + NAUTHOR + NSUBJ)

// ---------------------------------------------------------------------------
// C[N,128] = A[N,128] @ B[128,128]   (f32, A tile in LDS, B via L2)
// block: 256 threads, 64 rows per block; each thread: 8 rows x 4 cols
// ---------------------------------------------------------------------------
__global__ __launch_bounds__(256) void gemm128(const float* __restrict__ A,
                                               const float* __restrict__ B,
                                               float* __restrict__ C, int N) {
    __shared__ float As[64][132];  // pad 128->132 (float4-aligned, breaks bank stride)
    const int tid = threadIdx.x;
    const int row0 = blockIdx.x * 64;

    // load A tile: 64x128 floats = 2048 float4, 8 per thread
#pragma unroll
    for (int it = 0; it < 8; ++it) {
        int idx = it * 256 + tid;
        int r = idx >> 5, c4 = idx & 31;
        int row = row0 + r;
        if (row >= N) row = N - 1;  // clamp (dup reads ok, stores guarded)
        float4 v = reinterpret_cast<const float4*>(A)[(size_t)row * 32 + c4];
        *reinterpret_cast<float4*>(&As[r][c4 * 4]) = v;
    }
    __syncthreads();

    const int cg = tid & 31;   // col group: cols cg*4 .. cg*4+3
    const int rg = tid >> 5;   // row group: rows rg*8 .. rg*8+7
    float acc[8][4];
#pragma unroll
    for (int i = 0; i < 8; ++i)
#pragma unroll
        for (int j = 0; j < 4; ++j) acc[i][j] = 0.f;

#pragma unroll 4
    for (int k = 0; k < 128; ++k) {
        float4 b = reinterpret_cast<const float4*>(B)[k * 32 + cg];
#pragma unroll
        for (int i = 0; i < 8; ++i) {
            float a = As[rg * 8 + i][k];
            acc[i][0] += a * b.x;
            acc[i][1] += a * b.y;
            acc[i][2] += a * b.z;
            acc[i][3] += a * b.w;
        }
    }

#pragma unroll
    for (int i = 0; i < 8; ++i) {
        int row = row0 + rg * 8 + i;
        if (row < N) {
            float4 o = make_float4(acc[i][0], acc[i][1], acc[i][2], acc[i][3]);
            reinterpret_cast<float4*>(C)[(size_t)row * 32 + cg] = o;
        }
    }
}

// ---------------------------------------------------------------------------
// el[n,h] = sum_d hs[n, h*16+d] * al[h,d]
// ---------------------------------------------------------------------------
__global__ void el_reduce(const float* __restrict__ hs, const float* __restrict__ al,
                          float* __restrict__ el, int N) {
    int idx = blockIdx.x * blockDim.x + threadIdx.x;  // n*8 + h
    if (idx >= N * NHEAD) return;
    int n = idx >> 3, h = idx & 7;
    const float* hp = hs + (size_t)n * 128 + h * DHEAD;
    const float* ap = al + h * DHEAD;
    float s = 0.f;
#pragma unroll
    for (int d = 0; d < DHEAD; ++d) s += hp[d] * ap[d];
    el[idx] = s;
}

// ---------------------------------------------------------------------------
// er[n,h] = sum_k F[n,k] * Wred[k,h]      (Wred = W @ ar  : [128,8])
// ---------------------------------------------------------------------------
__global__ __launch_bounds__(256) void er_gemm(const float* __restrict__ F,
                                               const float* __restrict__ Wred,
                                               float* __restrict__ er, int N) {
    __shared__ float Wl[128 * 8];
    const int tid = threadIdx.x;
    for (int i = tid; i < 128 * 8; i += 256) Wl[i] = Wred[i];
    __syncthreads();
    int idx = blockIdx.x * 256 + tid;  // n*8 + h
    if (idx >= N * NHEAD) return;
    int n = idx >> 3, h = idx & 7;
    const float* f = F + (size_t)n * 128;
    float s = 0.f;
#pragma unroll 8
    for (int k = 0; k < 128; ++k) s += f[k] * Wl[k * 8 + h];
    er[idx] = s;
}

// ---------------------------------------------------------------------------
// Wred[r,k,h] = sum_d Ws[r,k,h*16+d] * ars[r,h,d]
// ---------------------------------------------------------------------------
__global__ void wred_kernel(const float* __restrict__ Ws4, const float* __restrict__ ars,
                            float* __restrict__ Wred) {
    int idx = blockIdx.x * blockDim.x + threadIdx.x;  // r*1024 + k*8 + h
    if (idx >= 4 * 128 * 8) return;
    int r = idx >> 10, rem = idx & 1023, k = rem >> 3, h = rem & 7;
    const float* W = Ws4 + r * 16384 + k * 128 + h * DHEAD;
    const float* ar = ars + r * 128 + h * DHEAD;
    float s = 0.f;
#pragma unroll
    for (int d = 0; d < DHEAD; ++d) s += W[d] * ar[d];
    Wred[idx] = s;
}

// ---------------------------------------------------------------------------
// Edge pass: for each edge e, each head h:
//   ee = exp(leaky_relu(el[src,h] + er[dst,h]))
//   denom[dst,h] += ee;  m[dst, h*16+d] += ee * hs[src, h*16+d]
// 32 lanes per edge (lane l handles floats l*4..l*4+3; head = l>>2)
// ---------------------------------------------------------------------------
__global__ __launch_bounds__(256) void edge_kernel(const int* __restrict__ src,
                                                   const int* __restrict__ dst,
                                                   const float* __restrict__ el,
                                                   const float* __restrict__ er,
                                                   const float* __restrict__ hs,
                                                   float* __restrict__ m,
                                                   float* __restrict__ denom, int E) {
    int t = blockIdx.x * 256 + threadIdx.x;
    int e = t >> 5;
    int l = t & 31;
    if (e >= E) return;
    int s = src[e], d = dst[e];
    int h = l >> 2;
    float ev = el[s * NHEAD + h] + er[d * NHEAD + h];
    ev = ev > 0.f ? ev : 0.2f * ev;
    float ee = expf(ev);
    if ((l & 3) == 0) atomicAdd(&denom[(size_t)d * NHEAD + h], ee);
    float4 hv = reinterpret_cast<const float4*>(hs)[(size_t)s * 32 + l];
    float* mp = m + (size_t)d * 128 + l * 4;
    atomicAdd(mp + 0, ee * hv.x);
    atomicAdd(mp + 1, ee * hv.y);
    atomicAdd(mp + 2, ee * hv.z);
    atomicAdd(mp + 3, ee * hv.w);
}

// ---------------------------------------------------------------------------
// out[n,c] (=|=0.5*|+=0.5*)  m[n,c]/max(denom[n,c/16],1e-9) + b[c]
// ---------------------------------------------------------------------------
__global__ void finalize(const float* __restrict__ m, const float* __restrict__ denom,
                         const float* __restrict__ b, float* __restrict__ out,
                         int N, int mode) {
    int idx = blockIdx.x * blockDim.x + threadIdx.x;  // n*128 + c
    if (idx >= N * 128) return;
    int n = idx >> 7, c = idx & 127;
    float dn = denom[(size_t)n * NHEAD + (c >> 4)];
    float v = m[idx] / fmaxf(dn, 1e-9f) + b[c];
    if (mode == 0)
        out[idx] = v;
    else if (mode == 1)
        out[idx] = 0.5f * v;
    else
        out[idx] += 0.5f * v;
}

// ---------------------------------------------------------------------------
extern "C" void kernel_launch(void* const* d_in, const int* in_sizes, int n_in,
                              void* d_out, int out_size, void* d_ws, size_t ws_size,
                              hipStream_t stream) {
    const float* Ws4 = (const float*)d_in[14];
    const float* als = (const float*)d_in[15];
    const float* ars = (const float*)d_in[16];
    const float* bs  = (const float*)d_in[17];
    float* out = (float*)d_out;

    char* wsp = (char*)d_ws;
    float* hs    = (float*)wsp; wsp += (size_t)NPAPER * 128 * 4;
    float* el    = (float*)wsp; wsp += (size_t)NPAPER * NHEAD * 4;
    float* er    = (float*)wsp; wsp += (size_t)NPAPER * NHEAD * 4;
    float* m     = (float*)wsp; wsp += (size_t)NPAPER * 128 * 4;
    float* denom = (float*)wsp; wsp += (size_t)NPAPER * NHEAD * 4;
    float* Wred  = (float*)wsp; wsp += 4096 * 4;

    wred_kernel<<<16, 256, 0, stream>>>(Ws4, ars, Wred);

    for (int i = 0; i < 2; ++i) {
        const float* fp = (const float*)d_in[0 + 3 * i];
        const float* fa = (const float*)d_in[1 + 3 * i];
        const float* fs = (const float*)d_in[2 + 3 * i];
        float* outi = out + (size_t)i * NTOT * 128;

        struct Rel {
            const float* fsrc; const float* fdst;
            const int* src; const int* dst;
            int Nsrc, Ndst, E, r; size_t off; int mode;
        } rels[4] = {
            // r0 pa: paper->author, out: author region, '='
            { fp, fa, (const int*)d_in[6],  (const int*)d_in[7],  NPAPER, NAUTHOR,
              in_sizes[6], 0, (size_t)NPAPER * 128, 0 },
            // r1 ap: author->paper, out: paper region, '=0.5*'
            { fa, fp, (const int*)d_in[8],  (const int*)d_in[9],  NAUTHOR, NPAPER,
              in_sizes[8], 1, 0, 1 },
            // r2 ps: paper->subject, out: subject region, '='
            { fp, fs, (const int*)d_in[10], (const int*)d_in[11], NPAPER, NSUBJ,
              in_sizes[10], 2, (size_t)(NPAPER + NAUTHOR) * 128, 0 },
            // r3 sp: subject->paper, out: paper region, '+=0.5*'
            { fs, fp, (const int*)d_in[12], (const int*)d_in[13], NSUBJ, NPAPER,
              in_sizes[12], 3, 0, 2 },
        };

        for (int rr = 0; rr < 4; ++rr) {
            const Rel& R = rels[rr];
            gemm128<<<(R.Nsrc + 63) / 64, 256, 0, stream>>>(
                R.fsrc, Ws4 + (size_t)R.r * 16384, hs, R.Nsrc);
            el_reduce<<<(R.Nsrc * NHEAD + 255) / 256, 256, 0, stream>>>(
                hs, als + R.r * 128, el, R.Nsrc);
            er_gemm<<<(R.Ndst * NHEAD + 255) / 256, 256, 0, stream>>>(
                R.fdst, Wred + R.r * 1024, er, R.Ndst);
            hipMemsetAsync(m, 0, (size_t)R.Ndst * 128 * 4, stream);
            hipMemsetAsync(denom, 0, (size_t)R.Ndst * NHEAD * 4, stream);
            int nthr = R.E * 32;
            edge_kernel<<<(nthr + 255) / 256, 256, 0, stream>>>(
                R.src, R.dst, el, er, hs, m, denom, R.E);
            finalize<<<(R.Ndst * 128 + 255) / 256, 256, 0, stream>>>(
                m, denom, bs + R.r * 128, outi + R.off, R.Ndst, R.mode);
        }
    }
}

// Round 2
// 1056.755 us; speedup vs baseline: 3.6607x; 3.6607x over previous
//
#include <hip/hip_runtime.h>

#define NHEAD 8
#define DHEAD 16
#define NPAPER 100000
#define NAUTHOR 60000
#define NSUBJ 1000
#define NTOT (NPAPER + NAUTHOR + NSUBJ)

// ---------------------------------------------------------------------------
// C[N,128] = A[N,128] @ B[128,128]   (f32, A tile in LDS, B via L2)
// ---------------------------------------------------------------------------
__global__ __launch_bounds__(256) void gemm128(const float* __restrict__ A,
                                               const float* __restrict__ B,
                                               float* __restrict__ C, int N) {
    __shared__ float As[64][132];
    const int tid = threadIdx.x;
    const int row0 = blockIdx.x * 64;

#pragma unroll
    for (int it = 0; it < 8; ++it) {
        int idx = it * 256 + tid;
        int r = idx >> 5, c4 = idx & 31;
        int row = row0 + r;
        if (row >= N) row = N - 1;
        float4 v = reinterpret_cast<const float4*>(A)[(size_t)row * 32 + c4];
        *reinterpret_cast<float4*>(&As[r][c4 * 4]) = v;
    }
    __syncthreads();

    const int cg = tid & 31;
    const int rg = tid >> 5;
    float acc[8][4];
#pragma unroll
    for (int i = 0; i < 8; ++i)
#pragma unroll
        for (int j = 0; j < 4; ++j) acc[i][j] = 0.f;

#pragma unroll 4
    for (int k = 0; k < 128; ++k) {
        float4 b = reinterpret_cast<const float4*>(B)[k * 32 + cg];
#pragma unroll
        for (int i = 0; i < 8; ++i) {
            float a = As[rg * 8 + i][k];
            acc[i][0] += a * b.x;
            acc[i][1] += a * b.y;
            acc[i][2] += a * b.z;
            acc[i][3] += a * b.w;
        }
    }

#pragma unroll
    for (int i = 0; i < 8; ++i) {
        int row = row0 + rg * 8 + i;
        if (row < N) {
            float4 o = make_float4(acc[i][0], acc[i][1], acc[i][2], acc[i][3]);
            reinterpret_cast<float4*>(C)[(size_t)row * 32 + cg] = o;
        }
    }
}

// el[n,h] = sum_d hs[n, h*16+d] * al[h,d]
__global__ void el_reduce(const float* __restrict__ hs, const float* __restrict__ al,
                          float* __restrict__ el, int N) {
    int idx = blockIdx.x * blockDim.x + threadIdx.x;
    if (idx >= N * NHEAD) return;
    int n = idx >> 3, h = idx & 7;
    const float* hp = hs + (size_t)n * 128 + h * DHEAD;
    const float* ap = al + h * DHEAD;
    float s = 0.f;
#pragma unroll
    for (int d = 0; d < DHEAD; ++d) s += hp[d] * ap[d];
    el[idx] = s;
}

// er[n,h] = sum_k F[n,k] * Wred[k,h]
__global__ __launch_bounds__(256) void er_gemm(const float* __restrict__ F,
                                               const float* __restrict__ Wred,
                                               float* __restrict__ er, int N) {
    __shared__ float Wl[128 * 8];
    const int tid = threadIdx.x;
    for (int i = tid; i < 128 * 8; i += 256) Wl[i] = Wred[i];
    __syncthreads();
    int idx = blockIdx.x * 256 + tid;
    if (idx >= N * NHEAD) return;
    int n = idx >> 3, h = idx & 7;
    const float* f = F + (size_t)n * 128;
    float s = 0.f;
#pragma unroll 8
    for (int k = 0; k < 128; ++k) s += f[k] * Wl[k * 8 + h];
    er[idx] = s;
}

// Wred[r,k,h] = sum_d Ws[r,k,h*16+d] * ars[r,h,d]
__global__ void wred_kernel(const float* __restrict__ Ws4, const float* __restrict__ ars,
                            float* __restrict__ Wred) {
    int idx = blockIdx.x * blockDim.x + threadIdx.x;
    if (idx >= 4 * 128 * 8) return;
    int r = idx >> 10, rem = idx & 1023, k = rem >> 3, h = rem & 7;
    const float* W = Ws4 + r * 16384 + k * 128 + h * DHEAD;
    const float* ar = ars + r * 128 + h * DHEAD;
    float s = 0.f;
#pragma unroll
    for (int d = 0; d < DHEAD; ++d) s += W[d] * ar[d];
    Wred[idx] = s;
}

// ---------------------------------------------------------------------------
// CSR build
// ---------------------------------------------------------------------------
__global__ void count_kernel(const int* __restrict__ dst, int* __restrict__ deg, int E) {
    int e = blockIdx.x * blockDim.x + threadIdx.x;
    if (e < E) atomicAdd(&deg[dst[e]], 1);
}

// pass 1: per-1024-chunk sums
__global__ __launch_bounds__(256) void scan_bsum(const int* __restrict__ deg,
                                                 int* __restrict__ bsums, int N) {
    int base = blockIdx.x * 1024 + threadIdx.x * 4;
    int s = 0;
#pragma unroll
    for (int j = 0; j < 4; ++j) {
        int i = base + j;
        if (i < N) s += deg[i];
    }
#pragma unroll
    for (int off = 32; off; off >>= 1) s += __shfl_down(s, off);
    __shared__ int wt[4];
    if ((threadIdx.x & 63) == 0) wt[threadIdx.x >> 6] = s;
    __syncthreads();
    if (threadIdx.x == 0) bsums[blockIdx.x] = wt[0] + wt[1] + wt[2] + wt[3];
}

// pass 2: exclusive scan of block sums (n <= 256), single block of 256
__global__ __launch_bounds__(256) void scan_small_excl(int* __restrict__ data, int n) {
    int t = threadIdx.x;
    int v = (t < n) ? data[t] : 0;
    int inc = v;
#pragma unroll
    for (int off = 1; off < 64; off <<= 1) {
        int u = __shfl_up(inc, off);
        if ((t & 63) >= off) inc += u;
    }
    __shared__ int wt[4];
    if ((t & 63) == 63) wt[t >> 6] = inc;
    __syncthreads();
    int wo = 0;
    for (int w = 0; w < (t >> 6); ++w) wo += wt[w];
    if (t < n) data[t] = wo + inc - v;
}

// pass 3: full exclusive scan -> row_ptr (+ cursor copy), row_ptr[N]=E
__global__ __launch_bounds__(256) void scan_final(const int* __restrict__ deg,
                                                  const int* __restrict__ bsums,
                                                  int* __restrict__ row_ptr,
                                                  int* __restrict__ cursor, int N) {
    int t = threadIdx.x;
    int base = blockIdx.x * 1024 + t * 4;
    int d[4];
    int s = 0;
#pragma unroll
    for (int j = 0; j < 4; ++j) {
        int i = base + j;
        d[j] = (i < N) ? deg[i] : 0;
        s += d[j];
    }
    int inc = s;
#pragma unroll
    for (int off = 1; off < 64; off <<= 1) {
        int u = __shfl_up(inc, off);
        if ((t & 63) >= off) inc += u;
    }
    __shared__ int wt[4];
    if ((t & 63) == 63) wt[t >> 6] = inc;
    __syncthreads();
    int start = bsums[blockIdx.x];
    for (int w = 0; w < (t >> 6); ++w) start += wt[w];
    start += inc - s;
#pragma unroll
    for (int j = 0; j < 4; ++j) {
        int i = base + j;
        if (i < N) {
            row_ptr[i] = start;
            cursor[i] = start;
        }
        start += d[j];
    }
    if (base < N && base + 4 >= N) row_ptr[N] = start;  // total
}

__global__ void scatter_kernel(const int* __restrict__ src, const int* __restrict__ dst,
                               int* __restrict__ cursor, int* __restrict__ srcs_out, int E) {
    int e = blockIdx.x * blockDim.x + threadIdx.x;
    if (e < E) {
        int p = atomicAdd(&cursor[dst[e]], 1);
        srcs_out[p] = src[e];
    }
}

// ---------------------------------------------------------------------------
// Fused dst-centric aggregation + softmax-normalize + bias + combine.
// 32 lanes per dst node; lane l owns out cols l*4..l*4+3, head = l>>2.
// ---------------------------------------------------------------------------
__global__ __launch_bounds__(256) void agg_kernel(const int* __restrict__ row_ptr,
                                                  const int* __restrict__ srcs,
                                                  const float* __restrict__ el,
                                                  const float* __restrict__ er,
                                                  const float* __restrict__ hs,
                                                  const float* __restrict__ b,
                                                  float* __restrict__ out,
                                                  int Ndst, int mode) {
    int g = (blockIdx.x * 256 + threadIdx.x) >> 5;
    int l = threadIdx.x & 31;
    if (g >= Ndst) return;
    int h = l >> 2;
    int p0 = row_ptr[g], p1 = row_ptr[g + 1];
    float erd = er[(size_t)g * NHEAD + h];
    float a0 = 0.f, a1 = 0.f, a2 = 0.f, a3 = 0.f, dsum = 0.f;
    for (int p = p0; p < p1; ++p) {
        int s = srcs[p];
        float ev = el[(size_t)s * NHEAD + h] + erd;
        ev = ev > 0.f ? ev : 0.2f * ev;
        float ee = __expf(ev);
        float4 hv = reinterpret_cast<const float4*>(hs)[(size_t)s * 32 + l];
        a0 += ee * hv.x;
        a1 += ee * hv.y;
        a2 += ee * hv.z;
        a3 += ee * hv.w;
        dsum += ee;
    }
    float inv = 1.f / fmaxf(dsum, 1e-9f);
    float4 bv = reinterpret_cast<const float4*>(b)[l];
    float4 o = make_float4(a0 * inv + bv.x, a1 * inv + bv.y,
                           a2 * inv + bv.z, a3 * inv + bv.w);
    float* op = out + (size_t)g * 128 + l * 4;
    if (mode == 0) {
        *reinterpret_cast<float4*>(op) = o;
    } else if (mode == 1) {
        o.x *= 0.5f; o.y *= 0.5f; o.z *= 0.5f; o.w *= 0.5f;
        *reinterpret_cast<float4*>(op) = o;
    } else {
        float4 prev = *reinterpret_cast<const float4*>(op);
        o.x = prev.x + 0.5f * o.x;
        o.y = prev.y + 0.5f * o.y;
        o.z = prev.z + 0.5f * o.z;
        o.w = prev.w + 0.5f * o.w;
        *reinterpret_cast<float4*>(op) = o;
    }
}

// ---------------------------------------------------------------------------
extern "C" void kernel_launch(void* const* d_in, const int* in_sizes, int n_in,
                              void* d_out, int out_size, void* d_ws, size_t ws_size,
                              hipStream_t stream) {
    const float* Ws4 = (const float*)d_in[14];
    const float* als = (const float*)d_in[15];
    const float* ars = (const float*)d_in[16];
    const float* bs  = (const float*)d_in[17];
    float* out = (float*)d_out;

    const int* e_src[4] = {(const int*)d_in[6], (const int*)d_in[8],
                           (const int*)d_in[10], (const int*)d_in[12]};
    const int* e_dst[4] = {(const int*)d_in[7], (const int*)d_in[9],
                           (const int*)d_in[11], (const int*)d_in[13]};
    const int Es[4] = {in_sizes[6], in_sizes[8], in_sizes[10], in_sizes[12]};
    const int Ndsts[4] = {NAUTHOR, NPAPER, NSUBJ, NPAPER};
    const int Nsrcs[4] = {NPAPER, NAUTHOR, NPAPER, NSUBJ};
    const size_t outoff[4] = {(size_t)NPAPER * 128, 0,
                              (size_t)(NPAPER + NAUTHOR) * 128, 0};
    const int modes[4] = {0, 1, 0, 2};

    // workspace carve (all 4-byte elements)
    char* wsp = (char*)d_ws;
    float* hs   = (float*)wsp; wsp += (size_t)NPAPER * 128 * 4;
    float* el   = (float*)wsp; wsp += (size_t)NPAPER * NHEAD * 4;
    float* er   = (float*)wsp; wsp += (size_t)NPAPER * NHEAD * 4;
    float* Wred = (float*)wsp; wsp += 4096 * 4;
    int* deg    = (int*)wsp;   wsp += (size_t)NPAPER * 4;
    int* cursor = (int*)wsp;   wsp += (size_t)NPAPER * 4;
    int* bsums  = (int*)wsp;   wsp += 256 * 4;
    int* row_ptr[4];
    int* srcs_csr[4];
    for (int r = 0; r < 4; ++r) {
        row_ptr[r] = (int*)wsp; wsp += (size_t)(((Ndsts[r] + 1 + 3) & ~3)) * 4;
    }
    for (int r = 0; r < 4; ++r) {
        srcs_csr[r] = (int*)wsp; wsp += (size_t)((Es[r] + 3) & ~3) * 4;
    }

    // ---- build CSR for each relation (edge lists shared by both inputs) ----
    for (int r = 0; r < 4; ++r) {
        int N = Ndsts[r], E = Es[r];
        int nb = (N + 1023) / 1024;
        hipMemsetAsync(deg, 0, (size_t)N * 4, stream);
        count_kernel<<<(E + 255) / 256, 256, 0, stream>>>(e_dst[r], deg, E);
        scan_bsum<<<nb, 256, 0, stream>>>(deg, bsums, N);
        scan_small_excl<<<1, 256, 0, stream>>>(bsums, nb);
        scan_final<<<nb, 256, 0, stream>>>(deg, bsums, row_ptr[r], cursor, N);
        scatter_kernel<<<(E + 255) / 256, 256, 0, stream>>>(e_src[r], e_dst[r], cursor,
                                                            srcs_csr[r], E);
    }

    wred_kernel<<<16, 256, 0, stream>>>(Ws4, ars, Wred);

    for (int i = 0; i < 2; ++i) {
        const float* feats[3] = {(const float*)d_in[0 + 3 * i],
                                 (const float*)d_in[1 + 3 * i],
                                 (const float*)d_in[2 + 3 * i]};
        // relation src/dst node-type index: 0=paper 1=author 2=subject
        const int srcT[4] = {0, 1, 0, 2};
        const int dstT[4] = {1, 0, 2, 0};
        float* outi = out + (size_t)i * NTOT * 128;

        for (int r = 0; r < 4; ++r) {
            const float* fsrc = feats[srcT[r]];
            const float* fdst = feats[dstT[r]];
            int Nsrc = Nsrcs[r], Ndst = Ndsts[r];
            gemm128<<<(Nsrc + 63) / 64, 256, 0, stream>>>(
                fsrc, Ws4 + (size_t)r * 16384, hs, Nsrc);
            el_reduce<<<(Nsrc * NHEAD + 255) / 256, 256, 0, stream>>>(
                hs, als + r * 128, el, Nsrc);
            er_gemm<<<(Ndst * NHEAD + 255) / 256, 256, 0, stream>>>(
                fdst, Wred + r * 1024, er, Ndst);
            agg_kernel<<<((Ndst * 32) + 255) / 256, 256, 0, stream>>>(
                row_ptr[r], srcs_csr[r], el, er, hs, bs + r * 128,
                outi + outoff[r], Ndst, modes[r]);
        }
    }
}

// Round 3
// 617.454 us; speedup vs baseline: 6.2652x; 1.7115x over previous
//
#include <hip/hip_runtime.h>

#define NHEAD 8
#define NPAPER 100000
#define NAUTHOR 60000
#define NSUBJ 1000
#define NTOT (NPAPER + NAUTHOR + NSUBJ)

typedef __attribute__((ext_vector_type(8))) short bf16x8;
typedef __attribute__((ext_vector_type(4))) float f32x4;

__device__ __forceinline__ unsigned short f2bf(float x) {
    unsigned int u = __builtin_bit_cast(unsigned int, x);
    u += 0x7fffu + ((u >> 16) & 1u);
    return (unsigned short)(u >> 16);
}
__device__ __forceinline__ float bf2f_lo(unsigned int v) {
    return __builtin_bit_cast(float, v << 16);
}
__device__ __forceinline__ float bf2f_hi(unsigned int v) {
    return __builtin_bit_cast(float, v & 0xffff0000u);
}

// ---------------------------------------------------------------------------
// prep: Wt[r][c][k] = bf16(W[r][k][c])   (B-operand, K-contiguous)
//       combo[r][n][k], n<8:  sum_d W[r][k][n*16+d]   * als[r][n][d]   (el)
//                       n>=8: sum_d W[r^1][k][h*16+d] * ars[r^1][h][d] (er of partner rel)
// ---------------------------------------------------------------------------
__global__ void prep_kernel(const float* __restrict__ Ws, const float* __restrict__ als,
                            const float* __restrict__ ars,
                            unsigned short* __restrict__ Wt,
                            unsigned short* __restrict__ combo) {
    int idx = blockIdx.x * 256 + threadIdx.x;
    if (idx < 65536) {
        int r = idx >> 14, rem = idx & 16383, c = rem >> 7, k = rem & 127;
        Wt[idx] = f2bf(Ws[(r << 14) + k * 128 + c]);
    } else if (idx < 65536 + 8192) {
        int j = idx - 65536;
        int r = j >> 11, rem = j & 2047, n = rem >> 7, k = rem & 127;
        int p = r ^ 1;  // partner relation: 0<->1, 2<->3
        const float *W, *a;
        if (n < 8) {
            W = Ws + (r << 14) + k * 128 + n * 16;
            a = als + r * 128 + n * 16;
        } else {
            int h = n - 8;
            W = Ws + (p << 14) + k * 128 + h * 16;
            a = ars + p * 128 + h * 16;
        }
        float s = 0.f;
#pragma unroll
        for (int d = 0; d < 16; ++d) s += W[d] * a[d];
        combo[j] = f2bf(s);
    }
}

// ---------------------------------------------------------------------------
// Fused projection: per 64-row block, computes (per weight set)
//   hs = A @ W (bf16 out), el = A @ Wlred, er = A @ Wred  via MFMA 16x16x32.
// A staged in LDS bf16, XOR-swizzled 16B chunks (chunk' = c8 ^ (row&15)).
// 4 waves; wave w owns rows w*16..w*16+15. 8 hs tiles + 1 combo tile per set.
// ---------------------------------------------------------------------------
template <int HAS2>
__global__ __launch_bounds__(256) void project_kernel(
    const float* __restrict__ A, int N,
    const unsigned short* __restrict__ Wt1, const unsigned short* __restrict__ cb1,
    unsigned short* __restrict__ hs1, float* __restrict__ el1, float* __restrict__ er1,
    const unsigned short* __restrict__ Wt2, const unsigned short* __restrict__ cb2,
    unsigned short* __restrict__ hs2, float* __restrict__ el2, float* __restrict__ er2) {
    __shared__ unsigned short Abf[64 * 128];  // 16 KiB
    const int tid = threadIdx.x;
    const int row0 = blockIdx.x * 64;

    // stage A: f32 -> bf16 into swizzled LDS (perfectly coalesced global reads)
#pragma unroll
    for (int it = 0; it < 4; ++it) {
        int id = it * 256 + tid;  // chunk id = r*16 + c8
        int r = id >> 4, c8 = id & 15;
        int row = row0 + r;
        if (row >= N) row = N - 1;
        const float4* ap = reinterpret_cast<const float4*>(A + (size_t)row * 128 + c8 * 8);
        float4 v0 = ap[0], v1 = ap[1];
        uint4 pk;
        pk.x = (unsigned)f2bf(v0.x) | ((unsigned)f2bf(v0.y) << 16);
        pk.y = (unsigned)f2bf(v0.z) | ((unsigned)f2bf(v0.w) << 16);
        pk.z = (unsigned)f2bf(v1.x) | ((unsigned)f2bf(v1.y) << 16);
        pk.w = (unsigned)f2bf(v1.z) | ((unsigned)f2bf(v1.w) << 16);
        *reinterpret_cast<uint4*>(&Abf[(r * 16 + (c8 ^ (r & 15))) * 8]) = pk;
    }
    __syncthreads();

    const int l = tid & 63;
    const int w = tid >> 6;
    const int lrow = l & 15;   // A row within tile / D col / B col
    const int lk8 = l >> 4;    // k-chunk 0..3

    f32x4 acc1[9], acc2[9];
#pragma unroll
    for (int t = 0; t < 9; ++t) {
        acc1[t] = f32x4{0.f, 0.f, 0.f, 0.f};
        acc2[t] = f32x4{0.f, 0.f, 0.f, 0.f};
    }

    const int arow = w * 16 + lrow;
#pragma unroll
    for (int ks = 0; ks < 4; ++ks) {
        int c8 = ks * 4 + lk8;
        bf16x8 af = *reinterpret_cast<const bf16x8*>(
            &Abf[(arow * 16 + (c8 ^ (arow & 15))) * 8]);
        const int koff = ks * 32 + lk8 * 8;
#pragma unroll
        for (int t = 0; t < 8; ++t) {
            bf16x8 b1 = *reinterpret_cast<const bf16x8*>(Wt1 + (t * 16 + lrow) * 128 + koff);
            acc1[t] = __builtin_amdgcn_mfma_f32_16x16x32_bf16(af, b1, acc1[t], 0, 0, 0);
        }
        bf16x8 c1 = *reinterpret_cast<const bf16x8*>(cb1 + lrow * 128 + koff);
        acc1[8] = __builtin_amdgcn_mfma_f32_16x16x32_bf16(af, c1, acc1[8], 0, 0, 0);
        if (HAS2) {
#pragma unroll
            for (int t = 0; t < 8; ++t) {
                bf16x8 b2 = *reinterpret_cast<const bf16x8*>(Wt2 + (t * 16 + lrow) * 128 + koff);
                acc2[t] = __builtin_amdgcn_mfma_f32_16x16x32_bf16(af, b2, acc2[t], 0, 0, 0);
            }
            bf16x8 c2 = *reinterpret_cast<const bf16x8*>(cb2 + lrow * 128 + koff);
            acc2[8] = __builtin_amdgcn_mfma_f32_16x16x32_bf16(af, c2, acc2[8], 0, 0, 0);
        }
    }

    // el / er from combo tile: D[m][n]: m = node row, n<8 -> el head, n>=8 -> er head
    const int grow0 = row0 + w * 16 + lk8 * 4;
#pragma unroll
    for (int r = 0; r < 4; ++r) {
        int row = grow0 + r;
        if (row < N) {
            if (lrow < 8) el1[row * 8 + lrow] = acc1[8][r];
            else er1[row * 8 + (lrow - 8)] = acc1[8][r];
            if (HAS2) {
                if (lrow < 8) el2[row * 8 + lrow] = acc2[8][r];
                else er2[row * 8 + (lrow - 8)] = acc2[8][r];
            }
        }
    }

    // hs out via LDS transpose (reuse Abf), coalesced 16B stores
    __syncthreads();
#pragma unroll
    for (int t = 0; t < 8; ++t) {
#pragma unroll
        for (int r = 0; r < 4; ++r) {
            int rl = w * 16 + lk8 * 4 + r;
            int col = t * 16 + lrow;
            int c8 = col >> 3;
            Abf[(rl * 16 + (c8 ^ (rl & 15))) * 8 + (col & 7)] = f2bf(acc1[t][r]);
        }
    }
    __syncthreads();
#pragma unroll
    for (int it = 0; it < 4; ++it) {
        int id = it * 256 + tid;
        int r = id >> 4, c8 = id & 15;
        int row = row0 + r;
        if (row < N) {
            uint4 v = *reinterpret_cast<const uint4*>(&Abf[(r * 16 + (c8 ^ (r & 15))) * 8]);
            *reinterpret_cast<uint4*>(hs1 + (size_t)row * 128 + c8 * 8) = v;
        }
    }
    if (HAS2) {
        __syncthreads();
#pragma unroll
        for (int t = 0; t < 8; ++t) {
#pragma unroll
            for (int r = 0; r < 4; ++r) {
                int rl = w * 16 + lk8 * 4 + r;
                int col = t * 16 + lrow;
                int c8 = col >> 3;
                Abf[(rl * 16 + (c8 ^ (rl & 15))) * 8 + (col & 7)] = f2bf(acc2[t][r]);
            }
        }
        __syncthreads();
#pragma unroll
        for (int it = 0; it < 4; ++it) {
            int id = it * 256 + tid;
            int r = id >> 4, c8 = id & 15;
            int row = row0 + r;
            if (row < N) {
                uint4 v = *reinterpret_cast<const uint4*>(&Abf[(r * 16 + (c8 ^ (r & 15))) * 8]);
                *reinterpret_cast<uint4*>(hs2 + (size_t)row * 128 + c8 * 8) = v;
            }
        }
    }
}

// ---------------------------------------------------------------------------
// CSR build (unchanged from round 2 — proven)
// ---------------------------------------------------------------------------
__global__ void count_kernel(const int* __restrict__ dst, int* __restrict__ deg, int E) {
    int e = blockIdx.x * blockDim.x + threadIdx.x;
    if (e < E) atomicAdd(&deg[dst[e]], 1);
}

__global__ __launch_bounds__(256) void scan_bsum(const int* __restrict__ deg,
                                                 int* __restrict__ bsums, int N) {
    int base = blockIdx.x * 1024 + threadIdx.x * 4;
    int s = 0;
#pragma unroll
    for (int j = 0; j < 4; ++j) {
        int i = base + j;
        if (i < N) s += deg[i];
    }
#pragma unroll
    for (int off = 32; off; off >>= 1) s += __shfl_down(s, off);
    __shared__ int wt[4];
    if ((threadIdx.x & 63) == 0) wt[threadIdx.x >> 6] = s;
    __syncthreads();
    if (threadIdx.x == 0) bsums[blockIdx.x] = wt[0] + wt[1] + wt[2] + wt[3];
}

__global__ __launch_bounds__(256) void scan_small_excl(int* __restrict__ data, int n) {
    int t = threadIdx.x;
    int v = (t < n) ? data[t] : 0;
    int inc = v;
#pragma unroll
    for (int off = 1; off < 64; off <<= 1) {
        int u = __shfl_up(inc, off);
        if ((t & 63) >= off) inc += u;
    }
    __shared__ int wt[4];
    if ((t & 63) == 63) wt[t >> 6] = inc;
    __syncthreads();
    int wo = 0;
    for (int w = 0; w < (t >> 6); ++w) wo += wt[w];
    if (t < n) data[t] = wo + inc - v;
}

__global__ __launch_bounds__(256) void scan_final(const int* __restrict__ deg,
                                                  const int* __restrict__ bsums,
                                                  int* __restrict__ row_ptr,
                                                  int* __restrict__ cursor, int N) {
    int t = threadIdx.x;
    int base = blockIdx.x * 1024 + t * 4;
    int d[4];
    int s = 0;
#pragma unroll
    for (int j = 0; j < 4; ++j) {
        int i = base + j;
        d[j] = (i < N) ? deg[i] : 0;
        s += d[j];
    }
    int inc = s;
#pragma unroll
    for (int off = 1; off < 64; off <<= 1) {
        int u = __shfl_up(inc, off);
        if ((t & 63) >= off) inc += u;
    }
    __shared__ int wt[4];
    if ((t & 63) == 63) wt[t >> 6] = inc;
    __syncthreads();
    int start = bsums[blockIdx.x];
    for (int w = 0; w < (t >> 6); ++w) start += wt[w];
    start += inc - s;
#pragma unroll
    for (int j = 0; j < 4; ++j) {
        int i = base + j;
        if (i < N) {
            row_ptr[i] = start;
            cursor[i] = start;
        }
        start += d[j];
    }
    if (base < N && base + 4 >= N) row_ptr[N] = start;
}

__global__ void scatter_kernel(const int* __restrict__ src, const int* __restrict__ dst,
                               int* __restrict__ cursor, int* __restrict__ srcs_out, int E) {
    int e = blockIdx.x * blockDim.x + threadIdx.x;
    if (e < E) {
        int p = atomicAdd(&cursor[dst[e]], 1);
        srcs_out[p] = src[e];
    }
}

// ---------------------------------------------------------------------------
// Aggregation: 16-lane groups (lane l owns cols l*8..l*8+7, head = l>>1),
// 4-edge unroll for MLP. nchunk>1: write partials (used for deg-150 subject rel).
// ---------------------------------------------------------------------------
__global__ __launch_bounds__(256) void agg_kernel(
    const int* __restrict__ row_ptr, const int* __restrict__ srcs,
    const float* __restrict__ el, const float* __restrict__ er,
    const unsigned short* __restrict__ hs, const float* __restrict__ b,
    float* __restrict__ out, int Ndst, int mode, int nchunk,
    float* __restrict__ m_part, float* __restrict__ denom_part) {
    int gid = (blockIdx.x * 256 + threadIdx.x) >> 4;
    int l = threadIdx.x & 15;
    if (gid >= Ndst * nchunk) return;
    int dst, ck;
    if (nchunk > 1) { dst = gid >> 3; ck = gid & 7; }  // nchunk == 8
    else { dst = gid; ck = 0; }
    int h = l >> 1;
    int p0 = row_ptr[dst], p1 = row_ptr[dst + 1];
    if (nchunk > 1) {
        int len = p1 - p0;
        int per = (len + 7) >> 3;
        int s0 = p0 + ck * per;
        int e0 = s0 + per;
        p1 = p1 < e0 ? p1 : e0;
        p0 = s0 < p1 ? s0 : p1;
    }
    float erd = er[(size_t)dst * 8 + h];

    float a[4][8];
    float dsv[4] = {0.f, 0.f, 0.f, 0.f};
#pragma unroll
    for (int u = 0; u < 4; ++u)
#pragma unroll
        for (int j = 0; j < 8; ++j) a[u][j] = 0.f;

    int p = p0;
    for (; p + 4 <= p1; p += 4) {
        int sx[4];
#pragma unroll
        for (int u = 0; u < 4; ++u) sx[u] = srcs[p + u];
        float ev[4];
        uint4 q[4];
#pragma unroll
        for (int u = 0; u < 4; ++u) {
            ev[u] = el[(size_t)sx[u] * 8 + h] + erd;
            q[u] = *reinterpret_cast<const uint4*>(hs + (size_t)sx[u] * 128 + l * 8);
        }
#pragma unroll
        for (int u = 0; u < 4; ++u) {
            float e = ev[u];
            e = e > 0.f ? e : 0.2f * e;
            float ee = __expf(e);
            dsv[u] += ee;
            a[u][0] += ee * bf2f_lo(q[u].x);
            a[u][1] += ee * bf2f_hi(q[u].x);
            a[u][2] += ee * bf2f_lo(q[u].y);
            a[u][3] += ee * bf2f_hi(q[u].y);
            a[u][4] += ee * bf2f_lo(q[u].z);
            a[u][5] += ee * bf2f_hi(q[u].z);
            a[u][6] += ee * bf2f_lo(q[u].w);
            a[u][7] += ee * bf2f_hi(q[u].w);
        }
    }
    for (; p < p1; ++p) {
        int s = srcs[p];
        float e = el[(size_t)s * 8 + h] + erd;
        e = e > 0.f ? e : 0.2f * e;
        float ee = __expf(e);
        uint4 q = *reinterpret_cast<const uint4*>(hs + (size_t)s * 128 + l * 8);
        dsv[0] += ee;
        a[0][0] += ee * bf2f_lo(q.x);
        a[0][1] += ee * bf2f_hi(q.x);
        a[0][2] += ee * bf2f_lo(q.y);
        a[0][3] += ee * bf2f_hi(q.y);
        a[0][4] += ee * bf2f_lo(q.z);
        a[0][5] += ee * bf2f_hi(q.z);
        a[0][6] += ee * bf2f_lo(q.w);
        a[0][7] += ee * bf2f_hi(q.w);
    }
#pragma unroll
    for (int j = 0; j < 8; ++j) a[0][j] += a[1][j] + a[2][j] + a[3][j];
    float dsum = dsv[0] + dsv[1] + dsv[2] + dsv[3];

    if (nchunk > 1) {
        float* mp = m_part + ((size_t)ck * Ndst + dst) * 128 + l * 8;
        float4 o0 = make_float4(a[0][0], a[0][1], a[0][2], a[0][3]);
        float4 o1 = make_float4(a[0][4], a[0][5], a[0][6], a[0][7]);
        reinterpret_cast<float4*>(mp)[0] = o0;
        reinterpret_cast<float4*>(mp)[1] = o1;
        if ((l & 1) == 0) denom_part[((size_t)ck * Ndst + dst) * 8 + h] = dsum;
        return;
    }

    float inv = 1.f / fmaxf(dsum, 1e-9f);
    const float4* bp = reinterpret_cast<const float4*>(b + l * 8);
    float4 b0 = bp[0], b1 = bp[1];
    float4 o0 = make_float4(a[0][0] * inv + b0.x, a[0][1] * inv + b0.y,
                            a[0][2] * inv + b0.z, a[0][3] * inv + b0.w);
    float4 o1 = make_float4(a[0][4] * inv + b1.x, a[0][5] * inv + b1.y,
                            a[0][6] * inv + b1.z, a[0][7] * inv + b1.w);
    float* op = out + (size_t)dst * 128 + l * 8;
    if (mode == 0) {
        reinterpret_cast<float4*>(op)[0] = o0;
        reinterpret_cast<float4*>(op)[1] = o1;
    } else if (mode == 1) {
        o0.x *= 0.5f; o0.y *= 0.5f; o0.z *= 0.5f; o0.w *= 0.5f;
        o1.x *= 0.5f; o1.y *= 0.5f; o1.z *= 0.5f; o1.w *= 0.5f;
        reinterpret_cast<float4*>(op)[0] = o0;
        reinterpret_cast<float4*>(op)[1] = o1;
    } else {
        float4 p0v = reinterpret_cast<const float4*>(op)[0];
        float4 p1v = reinterpret_cast<const float4*>(op)[1];
        o0.x = p0v.x + 0.5f * o0.x; o0.y = p0v.y + 0.5f * o0.y;
        o0.z = p0v.z + 0.5f * o0.z; o0.w = p0v.w + 0.5f * o0.w;
        o1.x = p1v.x + 0.5f * o1.x; o1.y = p1v.y + 0.5f * o1.y;
        o1.z = p1v.z + 0.5f * o1.z; o1.w = p1v.w + 0.5f * o1.w;
        reinterpret_cast<float4*>(op)[0] = o0;
        reinterpret_cast<float4*>(op)[1] = o1;
    }
}

// reduce 8 chunk-partials -> out (subject region, mode '=')
__global__ void finalize_part(const float* __restrict__ m_part,
                              const float* __restrict__ denom_part,
                              const float* __restrict__ b, float* __restrict__ out,
                              int Ndst) {
    int idx = blockIdx.x * 256 + threadIdx.x;  // dst*128 + c
    if (idx >= Ndst * 128) return;
    int dst = idx >> 7, c = idx & 127;
    int h = c >> 4;
    float s = 0.f, dn = 0.f;
#pragma unroll
    for (int ck = 0; ck < 8; ++ck) {
        s += m_part[((size_t)ck * Ndst + dst) * 128 + c];
        dn += denom_part[((size_t)ck * Ndst + dst) * 8 + h];
    }
    out[idx] = s / fmaxf(dn, 1e-9f) + b[c];
}

// ---------------------------------------------------------------------------
extern "C" void kernel_launch(void* const* d_in, const int* in_sizes, int n_in,
                              void* d_out, int out_size, void* d_ws, size_t ws_size,
                              hipStream_t stream) {
    const float* Ws4 = (const float*)d_in[14];
    const float* als = (const float*)d_in[15];
    const float* ars = (const float*)d_in[16];
    const float* bs = (const float*)d_in[17];
    float* out = (float*)d_out;

    const int* e_src[4] = {(const int*)d_in[6], (const int*)d_in[8],
                           (const int*)d_in[10], (const int*)d_in[12]};
    const int* e_dst[4] = {(const int*)d_in[7], (const int*)d_in[9],
                           (const int*)d_in[11], (const int*)d_in[13]};
    const int Es[4] = {in_sizes[6], in_sizes[8], in_sizes[10], in_sizes[12]};
    const int Ndsts[4] = {NAUTHOR, NPAPER, NSUBJ, NPAPER};
    const int Nsrcs[4] = {NPAPER, NAUTHOR, NPAPER, NSUBJ};

    // workspace carve (256B aligned)
    char* wsp = (char*)d_ws;
    auto carve = [&](size_t bytes) {
        char* p = wsp;
        wsp += (bytes + 255) & ~(size_t)255;
        return p;
    };
    unsigned short* Wt = (unsigned short*)carve(4 * 16384 * 2);
    unsigned short* combo = (unsigned short*)carve(4 * 2048 * 2);
    unsigned short* hsb[4];
    float* elb[4];
    float* erb[4];
    for (int r = 0; r < 4; ++r) hsb[r] = (unsigned short*)carve((size_t)Nsrcs[r] * 128 * 2);
    for (int r = 0; r < 4; ++r) elb[r] = (float*)carve((size_t)Nsrcs[r] * 8 * 4);
    for (int r = 0; r < 4; ++r) erb[r] = (float*)carve((size_t)Ndsts[r] * 8 * 4);
    int* deg = (int*)carve((size_t)NPAPER * 4);
    int* cursor = (int*)carve((size_t)NPAPER * 4);
    int* bsums = (int*)carve(1024);
    int* rp[4];
    int* scsr[4];
    for (int r = 0; r < 4; ++r) rp[r] = (int*)carve((size_t)(Ndsts[r] + 1) * 4);
    for (int r = 0; r < 4; ++r) scsr[r] = (int*)carve((size_t)Es[r] * 4);
    float* m_part = (float*)carve((size_t)8 * NSUBJ * 128 * 4);
    float* den_part = (float*)carve((size_t)8 * NSUBJ * 8 * 4);

    prep_kernel<<<288, 256, 0, stream>>>(Ws4, als, ars, Wt, combo);

    // CSR build (edge lists shared by both inputs)
    for (int r = 0; r < 4; ++r) {
        int N = Ndsts[r], E = Es[r];
        int nb = (N + 1023) / 1024;
        hipMemsetAsync(deg, 0, (size_t)N * 4, stream);
        count_kernel<<<(E + 255) / 256, 256, 0, stream>>>(e_dst[r], deg, E);
        scan_bsum<<<nb, 256, 0, stream>>>(deg, bsums, N);
        scan_small_excl<<<1, 256, 0, stream>>>(bsums, nb);
        scan_final<<<nb, 256, 0, stream>>>(deg, bsums, rp[r], cursor, N);
        scatter_kernel<<<(E + 255) / 256, 256, 0, stream>>>(e_src[r], e_dst[r], cursor,
                                                            scsr[r], E);
    }

    for (int i = 0; i < 2; ++i) {
        const float* fp = (const float*)d_in[0 + 3 * i];
        const float* fa = (const float*)d_in[1 + 3 * i];
        const float* fs = (const float*)d_in[2 + 3 * i];
        float* outi = out + (size_t)i * NTOT * 128;

        // projections: paper (W0 + W2, ers for r1/r3), author (W1, er r0),
        // subject (W3, er r2)
        project_kernel<1><<<(NPAPER + 63) / 64, 256, 0, stream>>>(
            fp, NPAPER, Wt + 0 * 16384, combo + 0 * 2048, hsb[0], elb[0], erb[1],
            Wt + 2 * 16384, combo + 2 * 2048, hsb[2], elb[2], erb[3]);
        project_kernel<0><<<(NAUTHOR + 63) / 64, 256, 0, stream>>>(
            fa, NAUTHOR, Wt + 1 * 16384, combo + 1 * 2048, hsb[1], elb[1], erb[0],
            Wt + 1 * 16384, combo + 1 * 2048, hsb[1], elb[1], erb[0]);
        project_kernel<0><<<(NSUBJ + 63) / 64, 256, 0, stream>>>(
            fs, NSUBJ, Wt + 3 * 16384, combo + 3 * 2048, hsb[3], elb[3], erb[2],
            Wt + 3 * 16384, combo + 3 * 2048, hsb[3], elb[3], erb[2]);

        // r0 pa: out author, '='
        {
            int groups = NAUTHOR;
            agg_kernel<<<(groups * 16 + 255) / 256, 256, 0, stream>>>(
                rp[0], scsr[0], elb[0], erb[0], hsb[0], bs + 0, outi + (size_t)NPAPER * 128,
                NAUTHOR, 0, 1, nullptr, nullptr);
        }
        // r1 ap: out paper, '=0.5*'
        {
            int groups = NPAPER;
            agg_kernel<<<(groups * 16 + 255) / 256, 256, 0, stream>>>(
                rp[1], scsr[1], elb[1], erb[1], hsb[1], bs + 128, outi, NPAPER, 1, 1,
                nullptr, nullptr);
        }
        // r2 ps: out subject via 8-way chunked partials
        {
            int groups = NSUBJ * 8;
            agg_kernel<<<(groups * 16 + 255) / 256, 256, 0, stream>>>(
                rp[2], scsr[2], elb[2], erb[2], hsb[2], bs + 256,
                outi + (size_t)(NPAPER + NAUTHOR) * 128, NSUBJ, 0, 8, m_part, den_part);
            finalize_part<<<(NSUBJ * 128 + 255) / 256, 256, 0, stream>>>(
                m_part, den_part, bs + 256, outi + (size_t)(NPAPER + NAUTHOR) * 128, NSUBJ);
        }
        // r3 sp: out paper, '+=0.5*'
        {
            int groups = NPAPER;
            agg_kernel<<<(groups * 16 + 255) / 256, 256, 0, stream>>>(
                rp[3], scsr[3], elb[3], erb[3], hsb[3], bs + 384, outi, NPAPER, 2, 1,
                nullptr, nullptr);
        }
    }
}

// Round 4
// 479.445 us; speedup vs baseline: 8.0686x; 1.2879x over previous
//
#include <hip/hip_runtime.h>

#define NHEAD 8
#define NPAPER 100000
#define NAUTHOR 60000
#define NSUBJ 1000
#define NTOT (NPAPER + NAUTHOR + NSUBJ)

typedef __attribute__((ext_vector_type(8))) short bf16x8;
typedef __attribute__((ext_vector_type(4))) float f32x4;

__device__ __forceinline__ unsigned short f2bf(float x) {
    unsigned int u = __builtin_bit_cast(unsigned int, x);
    u += 0x7fffu + ((u >> 16) & 1u);
    return (unsigned short)(u >> 16);
}
__device__ __forceinline__ float bf2f_lo(unsigned int v) {
    return __builtin_bit_cast(float, v << 16);
}
__device__ __forceinline__ float bf2f_hi(unsigned int v) {
    return __builtin_bit_cast(float, v & 0xffff0000u);
}

// ---------------------------------------------------------------------------
// prep: Wt[r][c][k] = bf16(W[r][k][c])   (B-operand, K-contiguous)
//       combo[r][n][k], n<8:  sum_d W[r][k][n*16+d]   * als[r][n][d]   (el)
//                       n>=8: sum_d W[r^1][k][h*16+d] * ars[r^1][h][d] (er of partner)
// ---------------------------------------------------------------------------
__global__ void prep_kernel(const float* __restrict__ Ws, const float* __restrict__ als,
                            const float* __restrict__ ars,
                            unsigned short* __restrict__ Wt,
                            unsigned short* __restrict__ combo) {
    int idx = blockIdx.x * 256 + threadIdx.x;
    if (idx < 65536) {
        int r = idx >> 14, rem = idx & 16383, c = rem >> 7, k = rem & 127;
        Wt[idx] = f2bf(Ws[(r << 14) + k * 128 + c]);
    } else if (idx < 65536 + 8192) {
        int j = idx - 65536;
        int r = j >> 11, rem = j & 2047, n = rem >> 7, k = rem & 127;
        int p = r ^ 1;
        const float *W, *a;
        if (n < 8) {
            W = Ws + (r << 14) + k * 128 + n * 16;
            a = als + r * 128 + n * 16;
        } else {
            int h = n - 8;
            W = Ws + (p << 14) + k * 128 + h * 16;
            a = ars + p * 128 + h * 16;
        }
        float s = 0.f;
#pragma unroll
        for (int d = 0; d < 16; ++d) s += W[d] * a[d];
        combo[j] = f2bf(s);
    }
}

// ---------------------------------------------------------------------------
// Projection, one weight set: hs = A@W (bf16), el/er from combo tile.
// Block: 256 thr / 4 waves / 64 rows. LDS: A 16 KB + W(9 tiles incl combo) 36 KB.
// All LDS XOR-swizzled by row for conflict-free ds_read_b128.
// ---------------------------------------------------------------------------
__global__ __launch_bounds__(256) void project1_kernel(
    const float* __restrict__ A, int N,
    const unsigned short* __restrict__ Wt, const unsigned short* __restrict__ cb,
    unsigned short* __restrict__ hs, float* __restrict__ el, float* __restrict__ er) {
    __shared__ unsigned short Abf[64 * 128];   // 16 KiB
    __shared__ unsigned short Wl[144 * 128];   // 36 KiB (rows 0-127: Wt, 128-143: combo)
    const int tid = threadIdx.x;
    const int row0 = blockIdx.x * 64;

    // stage A (f32 -> bf16, swizzled), 4 chunks/thread
#pragma unroll
    for (int it = 0; it < 4; ++it) {
        int id = it * 256 + tid;
        int r = id >> 4, c8 = id & 15;
        int row = row0 + r;
        if (row >= N) row = N - 1;
        const float4* ap = reinterpret_cast<const float4*>(A + (size_t)row * 128 + c8 * 8);
        float4 v0 = ap[0], v1 = ap[1];
        uint4 pk;
        pk.x = (unsigned)f2bf(v0.x) | ((unsigned)f2bf(v0.y) << 16);
        pk.y = (unsigned)f2bf(v0.z) | ((unsigned)f2bf(v0.w) << 16);
        pk.z = (unsigned)f2bf(v1.x) | ((unsigned)f2bf(v1.y) << 16);
        pk.w = (unsigned)f2bf(v1.z) | ((unsigned)f2bf(v1.w) << 16);
        *reinterpret_cast<uint4*>(&Abf[(r * 16 + (c8 ^ (r & 15))) * 8]) = pk;
    }
    // stage W: 144 rows x 16 chunks = 2304, 9 chunks/thread
#pragma unroll
    for (int it = 0; it < 9; ++it) {
        int id = it * 256 + tid;
        int r = id >> 4, c8 = id & 15;
        const unsigned short* srcp = (r < 128) ? (Wt + r * 128) : (cb + (r - 128) * 128);
        uint4 v = *reinterpret_cast<const uint4*>(srcp + c8 * 8);
        *reinterpret_cast<uint4*>(&Wl[(r * 16 + (c8 ^ (r & 15))) * 8]) = v;
    }
    __syncthreads();

    const int l = tid & 63;
    const int w = tid >> 6;
    const int lrow = l & 15;
    const int lk8 = l >> 4;

    // A fragments to registers (wave w owns rows w*16..w*16+15)
    bf16x8 af[4];
    const int arow = w * 16 + lrow;
#pragma unroll
    for (int ks = 0; ks < 4; ++ks) {
        int c8 = ks * 4 + lk8;
        af[ks] = *reinterpret_cast<const bf16x8*>(
            &Abf[(arow * 16 + (c8 ^ (arow & 15))) * 8]);
    }
    __syncthreads();  // all A reads done -> Abf reusable as output staging

#pragma unroll
    for (int t = 0; t < 9; ++t) {
        f32x4 acc = f32x4{0.f, 0.f, 0.f, 0.f};
#pragma unroll
        for (int ks = 0; ks < 4; ++ks) {
            int wrow = t * 16 + lrow;
            int c8 = ks * 4 + lk8;
            bf16x8 bf = *reinterpret_cast<const bf16x8*>(
                &Wl[(wrow * 16 + (c8 ^ (wrow & 15))) * 8]);
            acc = __builtin_amdgcn_mfma_f32_16x16x32_bf16(af[ks], bf, acc, 0, 0, 0);
        }
        if (t < 8) {
            // D: col = t*16+lrow, row(in tile) = lk8*4+r -> swizzled bf16 into Abf
#pragma unroll
            for (int r = 0; r < 4; ++r) {
                int rl = w * 16 + lk8 * 4 + r;
                int col = t * 16 + lrow;
                Abf[(rl * 16 + ((col >> 3) ^ (rl & 15))) * 8 + (col & 7)] = f2bf(acc[r]);
            }
        } else {
            // combo tile: col<8 -> el head, col>=8 -> er head
#pragma unroll
            for (int r = 0; r < 4; ++r) {
                int row = row0 + w * 16 + lk8 * 4 + r;
                if (row < N) {
                    if (lrow < 8) el[(size_t)row * 8 + lrow] = acc[r];
                    else er[(size_t)row * 8 + (lrow - 8)] = acc[r];
                }
            }
        }
    }
    __syncthreads();

    // coalesced hs store
#pragma unroll
    for (int it = 0; it < 4; ++it) {
        int id = it * 256 + tid;
        int r = id >> 4, c8 = id & 15;
        int row = row0 + r;
        if (row < N) {
            uint4 v = *reinterpret_cast<const uint4*>(&Abf[(r * 16 + (c8 ^ (r & 15))) * 8]);
            *reinterpret_cast<uint4*>(hs + (size_t)row * 128 + c8 * 8) = v;
        }
    }
}

// ---------------------------------------------------------------------------
// CSR build (proven)
// ---------------------------------------------------------------------------
__global__ void count_kernel(const int* __restrict__ dst, int* __restrict__ deg, int E) {
    int e = blockIdx.x * blockDim.x + threadIdx.x;
    if (e < E) atomicAdd(&deg[dst[e]], 1);
}

__global__ __launch_bounds__(256) void scan_bsum(const int* __restrict__ deg,
                                                 int* __restrict__ bsums, int N) {
    int base = blockIdx.x * 1024 + threadIdx.x * 4;
    int s = 0;
#pragma unroll
    for (int j = 0; j < 4; ++j) {
        int i = base + j;
        if (i < N) s += deg[i];
    }
#pragma unroll
    for (int off = 32; off; off >>= 1) s += __shfl_down(s, off);
    __shared__ int wt[4];
    if ((threadIdx.x & 63) == 0) wt[threadIdx.x >> 6] = s;
    __syncthreads();
    if (threadIdx.x == 0) bsums[blockIdx.x] = wt[0] + wt[1] + wt[2] + wt[3];
}

__global__ __launch_bounds__(256) void scan_small_excl(int* __restrict__ data, int n) {
    int t = threadIdx.x;
    int v = (t < n) ? data[t] : 0;
    int inc = v;
#pragma unroll
    for (int off = 1; off < 64; off <<= 1) {
        int u = __shfl_up(inc, off);
        if ((t & 63) >= off) inc += u;
    }
    __shared__ int wt[4];
    if ((t & 63) == 63) wt[t >> 6] = inc;
    __syncthreads();
    int wo = 0;
    for (int w = 0; w < (t >> 6); ++w) wo += wt[w];
    if (t < n) data[t] = wo + inc - v;
}

__global__ __launch_bounds__(256) void scan_final(const int* __restrict__ deg,
                                                  const int* __restrict__ bsums,
                                                  int* __restrict__ row_ptr,
                                                  int* __restrict__ cursor, int N) {
    int t = threadIdx.x;
    int base = blockIdx.x * 1024 + t * 4;
    int d[4];
    int s = 0;
#pragma unroll
    for (int j = 0; j < 4; ++j) {
        int i = base + j;
        d[j] = (i < N) ? deg[i] : 0;
        s += d[j];
    }
    int inc = s;
#pragma unroll
    for (int off = 1; off < 64; off <<= 1) {
        int u = __shfl_up(inc, off);
        if ((t & 63) >= off) inc += u;
    }
    __shared__ int wt[4];
    if ((t & 63) == 63) wt[t >> 6] = inc;
    __syncthreads();
    int start = bsums[blockIdx.x];
    for (int w = 0; w < (t >> 6); ++w) start += wt[w];
    start += inc - s;
#pragma unroll
    for (int j = 0; j < 4; ++j) {
        int i = base + j;
        if (i < N) {
            row_ptr[i] = start;
            cursor[i] = start;
        }
        start += d[j];
    }
    if (base < N && base + 4 >= N) row_ptr[N] = start;
}

__global__ void scatter_kernel(const int* __restrict__ src, const int* __restrict__ dst,
                               int* __restrict__ cursor, int* __restrict__ srcs_out, int E) {
    int e = blockIdx.x * blockDim.x + threadIdx.x;
    if (e < E) {
        int p = atomicAdd(&cursor[dst[e]], 1);
        srcs_out[p] = src[e];
    }
}

// ---------------------------------------------------------------------------
// accumulate helper macro body (16-lane group, 4-edge unroll)
// ---------------------------------------------------------------------------
#define ACC_LIST(rp, srcs, elp, erp, hsp, A, DS)                                   \
    {                                                                              \
        int p0 = rp[dst], p1 = rp[dst + 1];                                        \
        float erd = erp[(size_t)dst * 8 + h];                                      \
        float a4[4][8];                                                            \
        float dv[4] = {0.f, 0.f, 0.f, 0.f};                                        \
        _Pragma("unroll") for (int u = 0; u < 4; ++u)                              \
            _Pragma("unroll") for (int j = 0; j < 8; ++j) a4[u][j] = 0.f;          \
        int p = p0;                                                                \
        for (; p + 4 <= p1; p += 4) {                                              \
            int sx[4];                                                             \
            _Pragma("unroll") for (int u = 0; u < 4; ++u) sx[u] = srcs[p + u];     \
            float ev[4];                                                           \
            uint4 q[4];                                                            \
            _Pragma("unroll") for (int u = 0; u < 4; ++u) {                        \
                ev[u] = elp[(size_t)sx[u] * 8 + h] + erd;                          \
                q[u] = *reinterpret_cast<const uint4*>(hsp + (size_t)sx[u] * 128 + l * 8); \
            }                                                                      \
            _Pragma("unroll") for (int u = 0; u < 4; ++u) {                        \
                float e = ev[u];                                                   \
                e = e > 0.f ? e : 0.2f * e;                                        \
                float ee = __expf(e);                                              \
                dv[u] += ee;                                                       \
                a4[u][0] += ee * bf2f_lo(q[u].x);                                  \
                a4[u][1] += ee * bf2f_hi(q[u].x);                                  \
                a4[u][2] += ee * bf2f_lo(q[u].y);                                  \
                a4[u][3] += ee * bf2f_hi(q[u].y);                                  \
                a4[u][4] += ee * bf2f_lo(q[u].z);                                  \
                a4[u][5] += ee * bf2f_hi(q[u].z);                                  \
                a4[u][6] += ee * bf2f_lo(q[u].w);                                  \
                a4[u][7] += ee * bf2f_hi(q[u].w);                                  \
            }                                                                      \
        }                                                                          \
        for (; p < p1; ++p) {                                                      \
            int s = srcs[p];                                                       \
            float e = elp[(size_t)s * 8 + h] + erd;                                \
            e = e > 0.f ? e : 0.2f * e;                                            \
            float ee = __expf(e);                                                  \
            uint4 q = *reinterpret_cast<const uint4*>(hsp + (size_t)s * 128 + l * 8); \
            dv[0] += ee;                                                           \
            a4[0][0] += ee * bf2f_lo(q.x);                                         \
            a4[0][1] += ee * bf2f_hi(q.x);                                         \
            a4[0][2] += ee * bf2f_lo(q.y);                                         \
            a4[0][3] += ee * bf2f_hi(q.y);                                         \
            a4[0][4] += ee * bf2f_lo(q.z);                                         \
            a4[0][5] += ee * bf2f_hi(q.z);                                         \
            a4[0][6] += ee * bf2f_lo(q.w);                                         \
            a4[0][7] += ee * bf2f_hi(q.w);                                         \
        }                                                                          \
        _Pragma("unroll") for (int j = 0; j < 8; ++j)                              \
            A[j] = a4[0][j] + a4[1][j] + a4[2][j] + a4[3][j];                      \
        DS = dv[0] + dv[1] + dv[2] + dv[3];                                        \
    }

// fused r1+r3 paper aggregation: out = 0.5*(m1/d1+b1) + 0.5*(m3/d3+b3)
__global__ __launch_bounds__(256) void agg13_kernel(
    const int* __restrict__ rp1, const int* __restrict__ s1,
    const float* __restrict__ el1, const float* __restrict__ er1,
    const unsigned short* __restrict__ hs1, const float* __restrict__ b1,
    const int* __restrict__ rp3, const int* __restrict__ s3,
    const float* __restrict__ el3, const float* __restrict__ er3,
    const unsigned short* __restrict__ hs3, const float* __restrict__ b3,
    float* __restrict__ out, int Ndst) {
    int dst = (blockIdx.x * 256 + threadIdx.x) >> 4;
    int l = threadIdx.x & 15;
    if (dst >= Ndst) return;
    int h = l >> 1;

    float A1[8], A3[8], d1, d3;
    ACC_LIST(rp1, s1, el1, er1, hs1, A1, d1)
    ACC_LIST(rp3, s3, el3, er3, hs3, A3, d3)

    float i1 = 1.f / fmaxf(d1, 1e-9f);
    float i3 = 1.f / fmaxf(d3, 1e-9f);
    const float4* bp1 = reinterpret_cast<const float4*>(b1 + l * 8);
    const float4* bp3 = reinterpret_cast<const float4*>(b3 + l * 8);
    float4 b10 = bp1[0], b11 = bp1[1], b30 = bp3[0], b31 = bp3[1];
    float4 o0, o1;
    o0.x = 0.5f * ((A1[0] * i1 + b10.x) + (A3[0] * i3 + b30.x));
    o0.y = 0.5f * ((A1[1] * i1 + b10.y) + (A3[1] * i3 + b30.y));
    o0.z = 0.5f * ((A1[2] * i1 + b10.z) + (A3[2] * i3 + b30.z));
    o0.w = 0.5f * ((A1[3] * i1 + b10.w) + (A3[3] * i3 + b30.w));
    o1.x = 0.5f * ((A1[4] * i1 + b11.x) + (A3[4] * i3 + b31.x));
    o1.y = 0.5f * ((A1[5] * i1 + b11.y) + (A3[5] * i3 + b31.y));
    o1.z = 0.5f * ((A1[6] * i1 + b11.z) + (A3[6] * i3 + b31.z));
    o1.w = 0.5f * ((A1[7] * i1 + b11.w) + (A3[7] * i3 + b31.w));
    float* op = out + (size_t)dst * 128 + l * 8;
    reinterpret_cast<float4*>(op)[0] = o0;
    reinterpret_cast<float4*>(op)[1] = o1;
}

// single-list aggregation (r0 direct; r2 chunked partials)
__global__ __launch_bounds__(256) void agg_kernel(
    const int* __restrict__ row_ptr, const int* __restrict__ srcs,
    const float* __restrict__ el, const float* __restrict__ er,
    const unsigned short* __restrict__ hs, const float* __restrict__ b,
    float* __restrict__ out, int Ndst, int nchunk,
    float* __restrict__ m_part, float* __restrict__ denom_part) {
    int gid = (blockIdx.x * 256 + threadIdx.x) >> 4;
    int l = threadIdx.x & 15;
    if (gid >= Ndst * nchunk) return;
    int dst, ck;
    if (nchunk > 1) { dst = gid >> 3; ck = gid & 7; }
    else { dst = gid; ck = 0; }
    int h = l >> 1;
    int q0 = row_ptr[dst], q1 = row_ptr[dst + 1];
    if (nchunk > 1) {
        int len = q1 - q0;
        int per = (len + 7) >> 3;
        int c0 = q0 + ck * per;
        int c1 = c0 + per;
        q1 = q1 < c1 ? q1 : c1;
        q0 = c0 < q1 ? c0 : q1;
    }
    // inline version of ACC_LIST with explicit bounds q0/q1
    float erd = er[(size_t)dst * 8 + h];
    float a4[4][8];
    float dv[4] = {0.f, 0.f, 0.f, 0.f};
#pragma unroll
    for (int u = 0; u < 4; ++u)
#pragma unroll
        for (int j = 0; j < 8; ++j) a4[u][j] = 0.f;
    int p = q0;
    for (; p + 4 <= q1; p += 4) {
        int sx[4];
#pragma unroll
        for (int u = 0; u < 4; ++u) sx[u] = srcs[p + u];
        float ev[4];
        uint4 q[4];
#pragma unroll
        for (int u = 0; u < 4; ++u) {
            ev[u] = el[(size_t)sx[u] * 8 + h] + erd;
            q[u] = *reinterpret_cast<const uint4*>(hs + (size_t)sx[u] * 128 + l * 8);
        }
#pragma unroll
        for (int u = 0; u < 4; ++u) {
            float e = ev[u];
            e = e > 0.f ? e : 0.2f * e;
            float ee = __expf(e);
            dv[u] += ee;
            a4[u][0] += ee * bf2f_lo(q[u].x);
            a4[u][1] += ee * bf2f_hi(q[u].x);
            a4[u][2] += ee * bf2f_lo(q[u].y);
            a4[u][3] += ee * bf2f_hi(q[u].y);
            a4[u][4] += ee * bf2f_lo(q[u].z);
            a4[u][5] += ee * bf2f_hi(q[u].z);
            a4[u][6] += ee * bf2f_lo(q[u].w);
            a4[u][7] += ee * bf2f_hi(q[u].w);
        }
    }
    for (; p < q1; ++p) {
        int s = srcs[p];
        float e = el[(size_t)s * 8 + h] + erd;
        e = e > 0.f ? e : 0.2f * e;
        float ee = __expf(e);
        uint4 q = *reinterpret_cast<const uint4*>(hs + (size_t)s * 128 + l * 8);
        dv[0] += ee;
        a4[0][0] += ee * bf2f_lo(q.x);
        a4[0][1] += ee * bf2f_hi(q.x);
        a4[0][2] += ee * bf2f_lo(q.y);
        a4[0][3] += ee * bf2f_hi(q.y);
        a4[0][4] += ee * bf2f_lo(q.z);
        a4[0][5] += ee * bf2f_hi(q.z);
        a4[0][6] += ee * bf2f_lo(q.w);
        a4[0][7] += ee * bf2f_hi(q.w);
    }
    float A[8];
#pragma unroll
    for (int j = 0; j < 8; ++j) A[j] = a4[0][j] + a4[1][j] + a4[2][j] + a4[3][j];
    float dsum = dv[0] + dv[1] + dv[2] + dv[3];

    if (nchunk > 1) {
        float* mp = m_part + ((size_t)ck * Ndst + dst) * 128 + l * 8;
        reinterpret_cast<float4*>(mp)[0] = make_float4(A[0], A[1], A[2], A[3]);
        reinterpret_cast<float4*>(mp)[1] = make_float4(A[4], A[5], A[6], A[7]);
        if ((l & 1) == 0) denom_part[((size_t)ck * Ndst + dst) * 8 + h] = dsum;
        return;
    }
    float inv = 1.f / fmaxf(dsum, 1e-9f);
    const float4* bp = reinterpret_cast<const float4*>(b + l * 8);
    float4 b0 = bp[0], b1 = bp[1];
    float4 o0 = make_float4(A[0] * inv + b0.x, A[1] * inv + b0.y,
                            A[2] * inv + b0.z, A[3] * inv + b0.w);
    float4 o1 = make_float4(A[4] * inv + b1.x, A[5] * inv + b1.y,
                            A[6] * inv + b1.z, A[7] * inv + b1.w);
    float* op = out + (size_t)dst * 128 + l * 8;
    reinterpret_cast<float4*>(op)[0] = o0;
    reinterpret_cast<float4*>(op)[1] = o1;
}

__global__ void finalize_part(const float* __restrict__ m_part,
                              const float* __restrict__ denom_part,
                              const float* __restrict__ b, float* __restrict__ out,
                              int Ndst) {
    int idx = blockIdx.x * 256 + threadIdx.x;
    if (idx >= Ndst * 128) return;
    int dst = idx >> 7, c = idx & 127;
    int h = c >> 4;
    float s = 0.f, dn = 0.f;
#pragma unroll
    for (int ck = 0; ck < 8; ++ck) {
        s += m_part[((size_t)ck * Ndst + dst) * 128 + c];
        dn += denom_part[((size_t)ck * Ndst + dst) * 8 + h];
    }
    out[idx] = s / fmaxf(dn, 1e-9f) + b[c];
}

// ---------------------------------------------------------------------------
extern "C" void kernel_launch(void* const* d_in, const int* in_sizes, int n_in,
                              void* d_out, int out_size, void* d_ws, size_t ws_size,
                              hipStream_t stream) {
    const float* Ws4 = (const float*)d_in[14];
    const float* als = (const float*)d_in[15];
    const float* ars = (const float*)d_in[16];
    const float* bs = (const float*)d_in[17];
    float* out = (float*)d_out;

    const int* e_src[4] = {(const int*)d_in[6], (const int*)d_in[8],
                           (const int*)d_in[10], (const int*)d_in[12]};
    const int* e_dst[4] = {(const int*)d_in[7], (const int*)d_in[9],
                           (const int*)d_in[11], (const int*)d_in[13]};
    const int Es[4] = {in_sizes[6], in_sizes[8], in_sizes[10], in_sizes[12]};
    const int Ndsts[4] = {NAUTHOR, NPAPER, NSUBJ, NPAPER};
    const int Nsrcs[4] = {NPAPER, NAUTHOR, NPAPER, NSUBJ};

    char* wsp = (char*)d_ws;
    auto carve = [&](size_t bytes) {
        char* p = wsp;
        wsp += (bytes + 255) & ~(size_t)255;
        return p;
    };
    unsigned short* Wt = (unsigned short*)carve(4 * 16384 * 2);
    unsigned short* combo = (unsigned short*)carve(4 * 2048 * 2);
    unsigned short* hsb[4];
    float* elb[4];
    float* erb[4];
    for (int r = 0; r < 4; ++r) hsb[r] = (unsigned short*)carve((size_t)Nsrcs[r] * 128 * 2);
    for (int r = 0; r < 4; ++r) elb[r] = (float*)carve((size_t)Nsrcs[r] * 8 * 4);
    for (int r = 0; r < 4; ++r) erb[r] = (float*)carve((size_t)Ndsts[r] * 8 * 4);
    int* deg = (int*)carve((size_t)NPAPER * 4);
    int* cursor = (int*)carve((size_t)NPAPER * 4);
    int* bsums = (int*)carve(1024);
    int* rp[4];
    int* scsr[4];
    for (int r = 0; r < 4; ++r) rp[r] = (int*)carve((size_t)(Ndsts[r] + 1) * 4);
    for (int r = 0; r < 4; ++r) scsr[r] = (int*)carve((size_t)Es[r] * 4);
    float* m_part = (float*)carve((size_t)8 * NSUBJ * 128 * 4);
    float* den_part = (float*)carve((size_t)8 * NSUBJ * 8 * 4);

    prep_kernel<<<288, 256, 0, stream>>>(Ws4, als, ars, Wt, combo);

    for (int r = 0; r < 4; ++r) {
        int N = Ndsts[r], E = Es[r];
        int nb = (N + 1023) / 1024;
        hipMemsetAsync(deg, 0, (size_t)N * 4, stream);
        count_kernel<<<(E + 255) / 256, 256, 0, stream>>>(e_dst[r], deg, E);
        scan_bsum<<<nb, 256, 0, stream>>>(deg, bsums, N);
        scan_small_excl<<<1, 256, 0, stream>>>(bsums, nb);
        scan_final<<<nb, 256, 0, stream>>>(deg, bsums, rp[r], cursor, N);
        scatter_kernel<<<(E + 255) / 256, 256, 0, stream>>>(e_src[r], e_dst[r], cursor,
                                                            scsr[r], E);
    }

    for (int i = 0; i < 2; ++i) {
        const float* fp = (const float*)d_in[0 + 3 * i];
        const float* fa = (const float*)d_in[1 + 3 * i];
        const float* fs = (const float*)d_in[2 + 3 * i];
        float* outi = out + (size_t)i * NTOT * 128;

        // projections (per weight set; combo[r] -> el of r, er of partner r^1)
        project1_kernel<<<(NPAPER + 63) / 64, 256, 0, stream>>>(
            fp, NPAPER, Wt + 0 * 16384, combo + 0 * 2048, hsb[0], elb[0], erb[1]);
        project1_kernel<<<(NPAPER + 63) / 64, 256, 0, stream>>>(
            fp, NPAPER, Wt + 2 * 16384, combo + 2 * 2048, hsb[2], elb[2], erb[3]);
        project1_kernel<<<(NAUTHOR + 63) / 64, 256, 0, stream>>>(
            fa, NAUTHOR, Wt + 1 * 16384, combo + 1 * 2048, hsb[1], elb[1], erb[0]);
        project1_kernel<<<(NSUBJ + 63) / 64, 256, 0, stream>>>(
            fs, NSUBJ, Wt + 3 * 16384, combo + 3 * 2048, hsb[3], elb[3], erb[2]);

        // r0 pa -> author region
        agg_kernel<<<(NAUTHOR * 16 + 255) / 256, 256, 0, stream>>>(
            rp[0], scsr[0], elb[0], erb[0], hsb[0], bs + 0,
            outi + (size_t)NPAPER * 128, NAUTHOR, 1, nullptr, nullptr);
        // r1+r3 fused -> paper region
        agg13_kernel<<<(NPAPER * 16 + 255) / 256, 256, 0, stream>>>(
            rp[1], scsr[1], elb[1], erb[1], hsb[1], bs + 128,
            rp[3], scsr[3], elb[3], erb[3], hsb[3], bs + 384,
            outi, NPAPER);
        // r2 ps -> subject region (8-way chunked)
        agg_kernel<<<(NSUBJ * 8 * 16 + 255) / 256, 256, 0, stream>>>(
            rp[2], scsr[2], elb[2], erb[2], hsb[2], bs + 256,
            outi + (size_t)(NPAPER + NAUTHOR) * 128, NSUBJ, 8, m_part, den_part);
        finalize_part<<<(NSUBJ * 128 + 255) / 256, 256, 0, stream>>>(
            m_part, den_part, bs + 256, outi + (size_t)(NPAPER + NAUTHOR) * 128, NSUBJ);
    }
}

// Round 5
// 402.840 us; speedup vs baseline: 9.6030x; 1.1902x over previous
//
#include <hip/hip_runtime.h>

#define NHEAD 8
#define NPAPER 100000
#define NAUTHOR 60000
#define NSUBJ 1000
#define NTOT (NPAPER + NAUTHOR + NSUBJ)
#define NDEG 261000  // 60000 + 100000 + 1000 + 100000 (concat dst-node space)

typedef __attribute__((ext_vector_type(8))) short bf16x8;
typedef __attribute__((ext_vector_type(4))) float f32x4;

__device__ __forceinline__ unsigned short f2bf(float x) {
    unsigned int u = __builtin_bit_cast(unsigned int, x);
    u += 0x7fffu + ((u >> 16) & 1u);
    return (unsigned short)(u >> 16);
}
__device__ __forceinline__ float bf2f_lo(unsigned int v) {
    return __builtin_bit_cast(float, v << 16);
}
__device__ __forceinline__ float bf2f_hi(unsigned int v) {
    return __builtin_bit_cast(float, v & 0xffff0000u);
}

// ---------------------------------------------------------------------------
// prep: Wt[r][c][k] = bf16(W[r][k][c]); combo[r][n][k]: n<8 el-reduce (als[r]),
// n>=8 er-reduce of partner rel (ars[r^1]).
// ---------------------------------------------------------------------------
__global__ void prep_kernel(const float* __restrict__ Ws, const float* __restrict__ als,
                            const float* __restrict__ ars,
                            unsigned short* __restrict__ Wt,
                            unsigned short* __restrict__ combo) {
    int idx = blockIdx.x * 256 + threadIdx.x;
    if (idx < 65536) {
        int r = idx >> 14, rem = idx & 16383, c = rem >> 7, k = rem & 127;
        Wt[idx] = f2bf(Ws[(r << 14) + k * 128 + c]);
    } else if (idx < 65536 + 8192) {
        int j = idx - 65536;
        int r = j >> 11, rem = j & 2047, n = rem >> 7, k = rem & 127;
        int p = r ^ 1;
        const float *W, *a;
        if (n < 8) {
            W = Ws + (r << 14) + k * 128 + n * 16;
            a = als + r * 128 + n * 16;
        } else {
            int h = n - 8;
            W = Ws + (p << 14) + k * 128 + h * 16;
            a = ars + p * 128 + h * 16;
        }
        float s = 0.f;
#pragma unroll
        for (int d = 0; d < 16; ++d) s += W[d] * a[d];
        combo[j] = f2bf(s);
    }
}

// ---------------------------------------------------------------------------
// CSR build over concatenated dst-node space
// ---------------------------------------------------------------------------
struct CsrPtrs {
    const int* esrc[4];
    const int* edst[4];
    int ebase[5];   // edge prefix (concat edge space)
    int nbase[4];   // node base per relation
};

__global__ void csr_count(CsrPtrs cp, int* __restrict__ deg) {
    int idx = blockIdx.x * 256 + threadIdx.x;
    if (idx >= cp.ebase[4]) return;
    int r = 0;
    while (idx >= cp.ebase[r + 1]) ++r;
    int e = idx - cp.ebase[r];
    atomicAdd(&deg[cp.nbase[r] + cp.edst[r][e]], 1);
}

__global__ void csr_scatter(CsrPtrs cp, int* __restrict__ cursor,
                            int* __restrict__ srcs) {
    int idx = blockIdx.x * 256 + threadIdx.x;
    if (idx >= cp.ebase[4]) return;
    int r = 0;
    while (idx >= cp.ebase[r + 1]) ++r;
    int e = idx - cp.ebase[r];
    int p = atomicAdd(&cursor[cp.nbase[r] + cp.edst[r][e]], 1);
    srcs[p] = cp.esrc[r][e];
}

__global__ __launch_bounds__(256) void scan_bsum(const int* __restrict__ deg,
                                                 int* __restrict__ bsums, int N) {
    int base = blockIdx.x * 1024 + threadIdx.x * 4;
    int s = 0;
#pragma unroll
    for (int j = 0; j < 4; ++j) {
        int i = base + j;
        if (i < N) s += deg[i];
    }
#pragma unroll
    for (int off = 32; off; off >>= 1) s += __shfl_down(s, off);
    __shared__ int wt[4];
    if ((threadIdx.x & 63) == 0) wt[threadIdx.x >> 6] = s;
    __syncthreads();
    if (threadIdx.x == 0) bsums[blockIdx.x] = wt[0] + wt[1] + wt[2] + wt[3];
}

__global__ __launch_bounds__(256) void scan_small_excl(int* __restrict__ data, int n) {
    int t = threadIdx.x;
    int v = (t < n) ? data[t] : 0;
    int inc = v;
#pragma unroll
    for (int off = 1; off < 64; off <<= 1) {
        int u = __shfl_up(inc, off);
        if ((t & 63) >= off) inc += u;
    }
    __shared__ int wt[4];
    if ((t & 63) == 63) wt[t >> 6] = inc;
    __syncthreads();
    int wo = 0;
    for (int w = 0; w < (t >> 6); ++w) wo += wt[w];
    if (t < n) data[t] = wo + inc - v;
}

__global__ __launch_bounds__(256) void scan_final(const int* __restrict__ deg,
                                                  const int* __restrict__ bsums,
                                                  int* __restrict__ row_ptr,
                                                  int* __restrict__ cursor, int N) {
    int t = threadIdx.x;
    int base = blockIdx.x * 1024 + t * 4;
    int d[4];
    int s = 0;
#pragma unroll
    for (int j = 0; j < 4; ++j) {
        int i = base + j;
        d[j] = (i < N) ? deg[i] : 0;
        s += d[j];
    }
    int inc = s;
#pragma unroll
    for (int off = 1; off < 64; off <<= 1) {
        int u = __shfl_up(inc, off);
        if ((t & 63) >= off) inc += u;
    }
    __shared__ int wt[4];
    if ((t & 63) == 63) wt[t >> 6] = inc;
    __syncthreads();
    int start = bsums[blockIdx.x];
    for (int w = 0; w < (t >> 6); ++w) start += wt[w];
    start += inc - s;
#pragma unroll
    for (int j = 0; j < 4; ++j) {
        int i = base + j;
        if (i < N) {
            row_ptr[i] = start;
            cursor[i] = start;
        }
        start += d[j];
    }
    if (base < N && base + 4 >= N) row_ptr[N] = start;
}

// ---------------------------------------------------------------------------
// Batched projection: 8 tasks (2 inputs x {paper/W0, paper/W2, author/W1,
// subject/W3}). Flat grid; block -> task via boundary table.
// ---------------------------------------------------------------------------
struct ProjArgs {
    const float* A[8];
    const unsigned short* Wt[8];
    const unsigned short* cb[8];
    unsigned short* hs[8];
    float* el[8];
    float* er[8];
    int N[8];
    int blk0[9];
};

__global__ __launch_bounds__(256) void project_kernel(ProjArgs args) {
    int bb = blockIdx.x;
    int t = 0;
    while (bb >= args.blk0[t + 1]) ++t;
    const float* A = args.A[t];
    const unsigned short* Wt = args.Wt[t];
    const unsigned short* cb = args.cb[t];
    unsigned short* hs = args.hs[t];
    float* el = args.el[t];
    float* er = args.er[t];
    const int N = args.N[t];
    const int row0 = (bb - args.blk0[t]) * 64;

    __shared__ unsigned short Abf[64 * 128];   // 16 KiB
    __shared__ unsigned short Wl[144 * 128];   // 36 KiB
    const int tid = threadIdx.x;

#pragma unroll
    for (int it = 0; it < 4; ++it) {
        int id = it * 256 + tid;
        int r = id >> 4, c8 = id & 15;
        int row = row0 + r;
        if (row >= N) row = N - 1;
        const float4* ap = reinterpret_cast<const float4*>(A + (size_t)row * 128 + c8 * 8);
        float4 v0 = ap[0], v1 = ap[1];
        uint4 pk;
        pk.x = (unsigned)f2bf(v0.x) | ((unsigned)f2bf(v0.y) << 16);
        pk.y = (unsigned)f2bf(v0.z) | ((unsigned)f2bf(v0.w) << 16);
        pk.z = (unsigned)f2bf(v1.x) | ((unsigned)f2bf(v1.y) << 16);
        pk.w = (unsigned)f2bf(v1.z) | ((unsigned)f2bf(v1.w) << 16);
        *reinterpret_cast<uint4*>(&Abf[(r * 16 + (c8 ^ (r & 15))) * 8]) = pk;
    }
#pragma unroll
    for (int it = 0; it < 9; ++it) {
        int id = it * 256 + tid;
        int r = id >> 4, c8 = id & 15;
        const unsigned short* srcp = (r < 128) ? (Wt + r * 128) : (cb + (r - 128) * 128);
        uint4 v = *reinterpret_cast<const uint4*>(srcp + c8 * 8);
        *reinterpret_cast<uint4*>(&Wl[(r * 16 + (c8 ^ (r & 15))) * 8]) = v;
    }
    __syncthreads();

    const int l = tid & 63;
    const int w = tid >> 6;
    const int lrow = l & 15;
    const int lk8 = l >> 4;

    bf16x8 af[4];
    const int arow = w * 16 + lrow;
#pragma unroll
    for (int ks = 0; ks < 4; ++ks) {
        int c8 = ks * 4 + lk8;
        af[ks] = *reinterpret_cast<const bf16x8*>(
            &Abf[(arow * 16 + (c8 ^ (arow & 15))) * 8]);
    }
    __syncthreads();

#pragma unroll
    for (int t9 = 0; t9 < 9; ++t9) {
        f32x4 acc = f32x4{0.f, 0.f, 0.f, 0.f};
#pragma unroll
        for (int ks = 0; ks < 4; ++ks) {
            int wrow = t9 * 16 + lrow;
            int c8 = ks * 4 + lk8;
            bf16x8 bf = *reinterpret_cast<const bf16x8*>(
                &Wl[(wrow * 16 + (c8 ^ (wrow & 15))) * 8]);
            acc = __builtin_amdgcn_mfma_f32_16x16x32_bf16(af[ks], bf, acc, 0, 0, 0);
        }
        if (t9 < 8) {
#pragma unroll
            for (int r = 0; r < 4; ++r) {
                int rl = w * 16 + lk8 * 4 + r;
                int col = t9 * 16 + lrow;
                Abf[(rl * 16 + ((col >> 3) ^ (rl & 15))) * 8 + (col & 7)] = f2bf(acc[r]);
            }
        } else {
#pragma unroll
            for (int r = 0; r < 4; ++r) {
                int row = row0 + w * 16 + lk8 * 4 + r;
                if (row < N) {
                    if (lrow < 8) el[(size_t)row * 8 + lrow] = acc[r];
                    else er[(size_t)row * 8 + (lrow - 8)] = acc[r];
                }
            }
        }
    }
    __syncthreads();

#pragma unroll
    for (int it = 0; it < 4; ++it) {
        int id = it * 256 + tid;
        int r = id >> 4, c8 = id & 15;
        int row = row0 + r;
        if (row < N) {
            uint4 v = *reinterpret_cast<const uint4*>(&Abf[(r * 16 + (c8 ^ (r & 15))) * 8]);
            *reinterpret_cast<uint4*>(hs + (size_t)row * 128 + c8 * 8) = v;
        }
    }
}

// ---------------------------------------------------------------------------
// edge-list accumulate (16-lane group, 4-edge unroll); inlined
// ---------------------------------------------------------------------------
__device__ __forceinline__ void acc_list(int p0, int p1, float erd, int l, int h,
                                         const int* __restrict__ srcs,
                                         const float* __restrict__ el,
                                         const unsigned short* __restrict__ hs,
                                         float* A, float& DS) {
    float a4[4][8];
    float dv[4] = {0.f, 0.f, 0.f, 0.f};
#pragma unroll
    for (int u = 0; u < 4; ++u)
#pragma unroll
        for (int j = 0; j < 8; ++j) a4[u][j] = 0.f;
    int p = p0;
    for (; p + 4 <= p1; p += 4) {
        int sx[4];
#pragma unroll
        for (int u = 0; u < 4; ++u) sx[u] = srcs[p + u];
        float ev[4];
        uint4 q[4];
#pragma unroll
        for (int u = 0; u < 4; ++u) {
            ev[u] = el[(size_t)sx[u] * 8 + h] + erd;
            q[u] = *reinterpret_cast<const uint4*>(hs + (size_t)sx[u] * 128 + l * 8);
        }
#pragma unroll
        for (int u = 0; u < 4; ++u) {
            float e = ev[u];
            e = e > 0.f ? e : 0.2f * e;
            float ee = __expf(e);
            dv[u] += ee;
            a4[u][0] += ee * bf2f_lo(q[u].x);
            a4[u][1] += ee * bf2f_hi(q[u].x);
            a4[u][2] += ee * bf2f_lo(q[u].y);
            a4[u][3] += ee * bf2f_hi(q[u].y);
            a4[u][4] += ee * bf2f_lo(q[u].z);
            a4[u][5] += ee * bf2f_hi(q[u].z);
            a4[u][6] += ee * bf2f_lo(q[u].w);
            a4[u][7] += ee * bf2f_hi(q[u].w);
        }
    }
    for (; p < p1; ++p) {
        int s = srcs[p];
        float e = el[(size_t)s * 8 + h] + erd;
        e = e > 0.f ? e : 0.2f * e;
        float ee = __expf(e);
        uint4 q = *reinterpret_cast<const uint4*>(hs + (size_t)s * 128 + l * 8);
        dv[0] += ee;
        a4[0][0] += ee * bf2f_lo(q.x);
        a4[0][1] += ee * bf2f_hi(q.x);
        a4[0][2] += ee * bf2f_lo(q.y);
        a4[0][3] += ee * bf2f_hi(q.y);
        a4[0][4] += ee * bf2f_lo(q.z);
        a4[0][5] += ee * bf2f_hi(q.z);
        a4[0][6] += ee * bf2f_lo(q.w);
        a4[0][7] += ee * bf2f_hi(q.w);
    }
#pragma unroll
    for (int j = 0; j < 8; ++j) A[j] = a4[0][j] + a4[1][j] + a4[2][j] + a4[3][j];
    DS = dv[0] + dv[1] + dv[2] + dv[3];
}

// author region (rel0), both inputs in one grid
__global__ __launch_bounds__(256) void agg_author(
    const int* __restrict__ rp, const int* __restrict__ srcs,
    const float* __restrict__ el0, const float* __restrict__ el1,
    const float* __restrict__ er0, const float* __restrict__ er1,
    const unsigned short* __restrict__ hs0, const unsigned short* __restrict__ hs1,
    const float* __restrict__ b, float* __restrict__ out0, float* __restrict__ out1) {
    int g = (blockIdx.x * 256 + threadIdx.x) >> 4;
    int l = threadIdx.x & 15;
    if (g >= 2 * NAUTHOR) return;
    int inp = g >= NAUTHOR;
    int dst = inp ? g - NAUTHOR : g;
    const float* el = inp ? el1 : el0;
    const float* er = inp ? er1 : er0;
    const unsigned short* hs = inp ? hs1 : hs0;
    float* out = inp ? out1 : out0;
    int h = l >> 1;
    int p0 = rp[dst], p1 = rp[dst + 1];  // rel0 at nbase 0
    float erd = er[(size_t)dst * 8 + h];
    float A[8], ds;
    acc_list(p0, p1, erd, l, h, srcs, el, hs, A, ds);
    float inv = 1.f / fmaxf(ds, 1e-9f);
    const float4* bp = reinterpret_cast<const float4*>(b + l * 8);
    float4 b0 = bp[0], b1 = bp[1];
    float4 o0 = make_float4(A[0] * inv + b0.x, A[1] * inv + b0.y,
                            A[2] * inv + b0.z, A[3] * inv + b0.w);
    float4 o1 = make_float4(A[4] * inv + b1.x, A[5] * inv + b1.y,
                            A[6] * inv + b1.z, A[7] * inv + b1.w);
    float* op = out + (size_t)dst * 128 + l * 8;
    reinterpret_cast<float4*>(op)[0] = o0;
    reinterpret_cast<float4*>(op)[1] = o1;
}

// paper region: fused rel1 + rel3, both inputs
__global__ __launch_bounds__(256) void agg_paper(
    const int* __restrict__ rp, const int* __restrict__ srcs,
    const float* __restrict__ el1a, const float* __restrict__ el1b,  // rel1 el (author), inp0/1
    const float* __restrict__ er1a, const float* __restrict__ er1b,  // rel1 er (paper)
    const unsigned short* __restrict__ hs1a, const unsigned short* __restrict__ hs1b,
    const float* __restrict__ el3a, const float* __restrict__ el3b,  // rel3 el (subject)
    const float* __restrict__ er3a, const float* __restrict__ er3b,  // rel3 er (paper)
    const unsigned short* __restrict__ hs3a, const unsigned short* __restrict__ hs3b,
    const float* __restrict__ b1, const float* __restrict__ b3,
    float* __restrict__ out0, float* __restrict__ out1) {
    int g = (blockIdx.x * 256 + threadIdx.x) >> 4;
    int l = threadIdx.x & 15;
    if (g >= 2 * NPAPER) return;
    int inp = g >= NPAPER;
    int dst = inp ? g - NPAPER : g;
    const float* el1 = inp ? el1b : el1a;
    const float* er1 = inp ? er1b : er1a;
    const unsigned short* hs1 = inp ? hs1b : hs1a;
    const float* el3 = inp ? el3b : el3a;
    const float* er3 = inp ? er3b : er3a;
    const unsigned short* hs3 = inp ? hs3b : hs3a;
    float* out = inp ? out1 : out0;
    int h = l >> 1;

    float A1[8], A3[8], d1, d3;
    {
        int p0 = rp[60000 + dst], p1 = rp[60000 + dst + 1];
        acc_list(p0, p1, er1[(size_t)dst * 8 + h], l, h, srcs, el1, hs1, A1, d1);
    }
    {
        int p0 = rp[161000 + dst], p1 = rp[161000 + dst + 1];
        acc_list(p0, p1, er3[(size_t)dst * 8 + h], l, h, srcs, el3, hs3, A3, d3);
    }
    float i1 = 1.f / fmaxf(d1, 1e-9f);
    float i3 = 1.f / fmaxf(d3, 1e-9f);
    const float4* bp1 = reinterpret_cast<const float4*>(b1 + l * 8);
    const float4* bp3 = reinterpret_cast<const float4*>(b3 + l * 8);
    float4 b10 = bp1[0], b11 = bp1[1], b30 = bp3[0], b31 = bp3[1];
    float4 o0, o1;
    o0.x = 0.5f * ((A1[0] * i1 + b10.x) + (A3[0] * i3 + b30.x));
    o0.y = 0.5f * ((A1[1] * i1 + b10.y) + (A3[1] * i3 + b30.y));
    o0.z = 0.5f * ((A1[2] * i1 + b10.z) + (A3[2] * i3 + b30.z));
    o0.w = 0.5f * ((A1[3] * i1 + b10.w) + (A3[3] * i3 + b30.w));
    o1.x = 0.5f * ((A1[4] * i1 + b11.x) + (A3[4] * i3 + b31.x));
    o1.y = 0.5f * ((A1[5] * i1 + b11.y) + (A3[5] * i3 + b31.y));
    o1.z = 0.5f * ((A1[6] * i1 + b11.z) + (A3[6] * i3 + b31.z));
    o1.w = 0.5f * ((A1[7] * i1 + b11.w) + (A3[7] * i3 + b31.w));
    float* op = out + (size_t)dst * 128 + l * 8;
    reinterpret_cast<float4*>(op)[0] = o0;
    reinterpret_cast<float4*>(op)[1] = o1;
}

// subject region (rel2): one block per (input, dst); 16 chunks + LDS reduce
__global__ __launch_bounds__(256) void agg_subject(
    const int* __restrict__ rp, const int* __restrict__ srcs,
    const float* __restrict__ el0, const float* __restrict__ el1,
    const float* __restrict__ er0, const float* __restrict__ er1,
    const unsigned short* __restrict__ hs0, const unsigned short* __restrict__ hs1,
    const float* __restrict__ b, float* __restrict__ out0, float* __restrict__ out1) {
    int blk = blockIdx.x;
    int inp = blk >= NSUBJ;
    int dst = inp ? blk - NSUBJ : blk;
    const float* el = inp ? el1 : el0;
    const float* er = inp ? er1 : er0;
    const unsigned short* hs = inp ? hs1 : hs0;
    float* out = inp ? out1 : out0;
    int gl = threadIdx.x >> 4;
    int l = threadIdx.x & 15;
    int h = l >> 1;
    int p0 = rp[160000 + dst], p1 = rp[160000 + dst + 1];
    float erd = er[(size_t)dst * 8 + h];
    float a[8];
#pragma unroll
    for (int j = 0; j < 8; ++j) a[j] = 0.f;
    float dsum = 0.f;
    for (int p = p0 + gl; p < p1; p += 16) {
        int s = srcs[p];
        float e = el[(size_t)s * 8 + h] + erd;
        e = e > 0.f ? e : 0.2f * e;
        float ee = __expf(e);
        uint4 q = *reinterpret_cast<const uint4*>(hs + (size_t)s * 128 + l * 8);
        dsum += ee;
        a[0] += ee * bf2f_lo(q.x);
        a[1] += ee * bf2f_hi(q.x);
        a[2] += ee * bf2f_lo(q.y);
        a[3] += ee * bf2f_hi(q.y);
        a[4] += ee * bf2f_lo(q.z);
        a[5] += ee * bf2f_hi(q.z);
        a[6] += ee * bf2f_lo(q.w);
        a[7] += ee * bf2f_hi(q.w);
    }
    __shared__ float Am[16][128];
    __shared__ float Dm[16][8];
#pragma unroll
    for (int j = 0; j < 8; ++j) Am[gl][l * 8 + j] = a[j];
    if ((l & 1) == 0) Dm[gl][h] = dsum;
    __syncthreads();
    int c = threadIdx.x;
    if (c < 128) {
        float s = 0.f, dn = 0.f;
        int hh = c >> 4;
#pragma unroll
        for (int g = 0; g < 16; ++g) {
            s += Am[g][c];
            dn += Dm[g][hh];
        }
        out[(size_t)dst * 128 + c] = s / fmaxf(dn, 1e-9f) + b[c];
    }
}

// ---------------------------------------------------------------------------
extern "C" void kernel_launch(void* const* d_in, const int* in_sizes, int n_in,
                              void* d_out, int out_size, void* d_ws, size_t ws_size,
                              hipStream_t stream) {
    const float* Ws4 = (const float*)d_in[14];
    const float* als = (const float*)d_in[15];
    const float* ars = (const float*)d_in[16];
    const float* bs = (const float*)d_in[17];
    float* out = (float*)d_out;

    const int Es[4] = {in_sizes[6], in_sizes[8], in_sizes[10], in_sizes[12]};
    const int Nsrcs[4] = {NPAPER, NAUTHOR, NPAPER, NSUBJ};
    const int Ndsts[4] = {NAUTHOR, NPAPER, NSUBJ, NPAPER};
    const int Etot = Es[0] + Es[1] + Es[2] + Es[3];

    char* wsp = (char*)d_ws;
    auto carve = [&](size_t bytes) {
        char* p = wsp;
        wsp += (bytes + 255) & ~(size_t)255;
        return p;
    };
    unsigned short* Wt = (unsigned short*)carve(4 * 16384 * 2);
    unsigned short* combo = (unsigned short*)carve(4 * 2048 * 2);
    unsigned short* hsb[2][4];
    float* elb[2][4];
    float* erb[2][4];
    for (int i = 0; i < 2; ++i)
        for (int r = 0; r < 4; ++r) {
            hsb[i][r] = (unsigned short*)carve((size_t)Nsrcs[r] * 128 * 2);
            elb[i][r] = (float*)carve((size_t)Nsrcs[r] * 8 * 4);
            erb[i][r] = (float*)carve((size_t)Ndsts[r] * 8 * 4);
        }
    int* deg = (int*)carve((size_t)NDEG * 4);
    int* cursor = (int*)carve((size_t)NDEG * 4);
    int* bsums = (int*)carve(1024);
    int* rp = (int*)carve((size_t)(NDEG + 1) * 4);
    int* scsr = (int*)carve((size_t)Etot * 4);

    // ---- CSR (concat) ----
    CsrPtrs cp;
    cp.esrc[0] = (const int*)d_in[6];  cp.edst[0] = (const int*)d_in[7];
    cp.esrc[1] = (const int*)d_in[8];  cp.edst[1] = (const int*)d_in[9];
    cp.esrc[2] = (const int*)d_in[10]; cp.edst[2] = (const int*)d_in[11];
    cp.esrc[3] = (const int*)d_in[12]; cp.edst[3] = (const int*)d_in[13];
    cp.ebase[0] = 0;
    for (int r = 0; r < 4; ++r) cp.ebase[r + 1] = cp.ebase[r] + Es[r];
    cp.nbase[0] = 0;
    cp.nbase[1] = 60000;
    cp.nbase[2] = 160000;
    cp.nbase[3] = 161000;

    prep_kernel<<<288, 256, 0, stream>>>(Ws4, als, ars, Wt, combo);
    hipMemsetAsync(deg, 0, (size_t)NDEG * 4, stream);
    csr_count<<<(Etot + 255) / 256, 256, 0, stream>>>(cp, deg);
    int nb = (NDEG + 1023) / 1024;  // 255
    scan_bsum<<<nb, 256, 0, stream>>>(deg, bsums, NDEG);
    scan_small_excl<<<1, 256, 0, stream>>>(bsums, nb);
    scan_final<<<nb, 256, 0, stream>>>(deg, bsums, rp, cursor, NDEG);
    csr_scatter<<<(Etot + 255) / 256, 256, 0, stream>>>(cp, cursor, scsr);

    // ---- batched projection (8 tasks) ----
    ProjArgs pa;
    int blk = 0;
    int ti = 0;
    for (int i = 0; i < 2; ++i) {
        const float* feats[3] = {(const float*)d_in[0 + 3 * i],
                                 (const float*)d_in[1 + 3 * i],
                                 (const float*)d_in[2 + 3 * i]};
        const int srcT[4] = {0, 2, 1, 3};  // task order: p/W0, p/W2, a/W1, s/W3
        for (int k = 0; k < 4; ++k) {
            int r = srcT[k];
            const int featT[4] = {0, 1, 0, 2};  // rel -> src node type
            const float* A = feats[featT[r]];
            int N = Nsrcs[r];
            pa.A[ti] = A;
            pa.Wt[ti] = Wt + (size_t)r * 16384;
            pa.cb[ti] = combo + (size_t)r * 2048;
            pa.hs[ti] = hsb[i][r];
            pa.el[ti] = elb[i][r];
            pa.er[ti] = erb[i][r ^ 1];
            pa.N[ti] = N;
            pa.blk0[ti] = blk;
            blk += (N + 63) / 64;
            ++ti;
        }
    }
    pa.blk0[8] = blk;
    project_kernel<<<blk, 256, 0, stream>>>(pa);

    float* out0 = out;
    float* out1 = out + (size_t)NTOT * 128;

    // rel0 -> author region
    agg_author<<<(2 * NAUTHOR * 16 + 255) / 256, 256, 0, stream>>>(
        rp, scsr, elb[0][0], elb[1][0], erb[0][0], erb[1][0], hsb[0][0], hsb[1][0],
        bs + 0, out0 + (size_t)NPAPER * 128, out1 + (size_t)NPAPER * 128);
    // rel1+rel3 -> paper region
    agg_paper<<<(2 * NPAPER * 16 + 255) / 256, 256, 0, stream>>>(
        rp, scsr,
        elb[0][1], elb[1][1], erb[0][1], erb[1][1], hsb[0][1], hsb[1][1],
        elb[0][3], elb[1][3], erb[0][3], erb[1][3], hsb[0][3], hsb[1][3],
        bs + 128, bs + 384, out0, out1);
    // rel2 -> subject region
    agg_subject<<<2 * NSUBJ, 256, 0, stream>>>(
        rp, scsr, elb[0][2], elb[1][2], erb[0][2], erb[1][2], hsb[0][2], hsb[1][2],
        bs + 256, out0 + (size_t)(NPAPER + NAUTHOR) * 128,
        out1 + (size_t)(NPAPER + NAUTHOR) * 128);
}

// Round 6
// 384.026 us; speedup vs baseline: 10.0734x; 1.0490x over previous
//
#include <hip/hip_runtime.h>

#define NHEAD 8
#define NPAPER 100000
#define NAUTHOR 60000
#define NSUBJ 1000
#define NTOT (NPAPER + NAUTHOR + NSUBJ)
#define NDEG 261000  // author(60000) + paper(100000) + subject(1000) + paper(100000)

typedef __attribute__((ext_vector_type(8))) short bf16x8;
typedef __attribute__((ext_vector_type(4))) float f32x4;

__device__ __forceinline__ unsigned short f2bf(float x) {
    unsigned int u = __builtin_bit_cast(unsigned int, x);
    u += 0x7fffu + ((u >> 16) & 1u);
    return (unsigned short)(u >> 16);
}
__device__ __forceinline__ float bf2f_lo(unsigned int v) {
    return __builtin_bit_cast(float, v << 16);
}
__device__ __forceinline__ float bf2f_hi(unsigned int v) {
    return __builtin_bit_cast(float, v & 0xffff0000u);
}

// ---------------------------------------------------------------------------
// prep (+ deg zero): Wt[r][c][k] = bf16(W[r][k][c]); combo[r][n][k]:
// n<8 el-reduce (als[r]), n>=8 er-reduce of partner rel (ars[r^1]).
// blocks >= 288 zero the degree array.
// ---------------------------------------------------------------------------
__global__ void prep_kernel(const float* __restrict__ Ws, const float* __restrict__ als,
                            const float* __restrict__ ars,
                            unsigned short* __restrict__ Wt,
                            unsigned short* __restrict__ combo, int* __restrict__ deg) {
    int b = blockIdx.x;
    if (b >= 288) {
        int idx = (b - 288) * 1024 + threadIdx.x * 4;
        if (idx < NDEG) *reinterpret_cast<int4*>(&deg[idx]) = int4{0, 0, 0, 0};
        return;
    }
    int idx = b * 256 + threadIdx.x;
    if (idx < 65536) {
        int r = idx >> 14, rem = idx & 16383, c = rem >> 7, k = rem & 127;
        Wt[idx] = f2bf(Ws[(r << 14) + k * 128 + c]);
    } else if (idx < 65536 + 8192) {
        int j = idx - 65536;
        int r = j >> 11, rem = j & 2047, n = rem >> 7, k = rem & 127;
        int p = r ^ 1;
        const float *W, *a;
        if (n < 8) {
            W = Ws + (r << 14) + k * 128 + n * 16;
            a = als + r * 128 + n * 16;
        } else {
            int h = n - 8;
            W = Ws + (p << 14) + k * 128 + h * 16;
            a = ars + p * 128 + h * 16;
        }
        float s = 0.f;
#pragma unroll
        for (int d = 0; d < 16; ++d) s += W[d] * a[d];
        combo[j] = f2bf(s);
    }
}

// ---------------------------------------------------------------------------
// Projection helpers
// ---------------------------------------------------------------------------
__device__ __forceinline__ void stage_W(unsigned short* Wl, const unsigned short* Wt,
                                        const unsigned short* cb, int tid) {
#pragma unroll
    for (int it = 0; it < 9; ++it) {
        int id = it * 256 + tid;
        int r = id >> 4, c8 = id & 15;
        const unsigned short* srcp = (r < 128) ? (Wt + r * 128) : (cb + (r - 128) * 128);
        uint4 v = *reinterpret_cast<const uint4*>(srcp + c8 * 8);
        *reinterpret_cast<uint4*>(&Wl[(r * 16 + (c8 ^ (r & 15))) * 8]) = v;
    }
}

__device__ __forceinline__ void mfma_set(const unsigned short* Wl, unsigned short* Abf,
                                         const bf16x8* af, int tid, int row0, int N,
                                         float* __restrict__ el, float* __restrict__ er) {
    const int l = tid & 63, w = tid >> 6, lrow = l & 15, lk8 = l >> 4;
#pragma unroll
    for (int t9 = 0; t9 < 9; ++t9) {
        f32x4 acc = f32x4{0.f, 0.f, 0.f, 0.f};
#pragma unroll
        for (int ks = 0; ks < 4; ++ks) {
            int wrow = t9 * 16 + lrow;
            int c8 = ks * 4 + lk8;
            bf16x8 bf = *reinterpret_cast<const bf16x8*>(
                &Wl[(wrow * 16 + (c8 ^ (wrow & 15))) * 8]);
            acc = __builtin_amdgcn_mfma_f32_16x16x32_bf16(af[ks], bf, acc, 0, 0, 0);
        }
        if (t9 < 8) {
#pragma unroll
            for (int r = 0; r < 4; ++r) {
                int rl = w * 16 + lk8 * 4 + r;
                int col = t9 * 16 + lrow;
                Abf[(rl * 16 + ((col >> 3) ^ (rl & 15))) * 8 + (col & 7)] = f2bf(acc[r]);
            }
        } else {
#pragma unroll
            for (int r = 0; r < 4; ++r) {
                int row = row0 + w * 16 + lk8 * 4 + r;
                if (row < N) {
                    if (lrow < 8) el[(size_t)row * 8 + lrow] = acc[r];
                    else er[(size_t)row * 8 + (lrow - 8)] = acc[r];
                }
            }
        }
    }
}

__device__ __forceinline__ void store_hs(const unsigned short* Abf,
                                         unsigned short* __restrict__ hs, int tid,
                                         int row0, int N) {
#pragma unroll
    for (int it = 0; it < 4; ++it) {
        int id = it * 256 + tid;
        int r = id >> 4, c8 = id & 15;
        int row = row0 + r;
        if (row < N) {
            uint4 v = *reinterpret_cast<const uint4*>(&Abf[(r * 16 + (c8 ^ (r & 15))) * 8]);
            *reinterpret_cast<uint4*>(hs + (size_t)row * 128 + c8 * 8) = v;
        }
    }
}

// ---------------------------------------------------------------------------
// Fused projection + CSR count. Blocks [0, cblk): edge-degree count.
// Blocks [cblk, ...): 6 projection tasks; paper tasks run two weight sets
// (W reload into LDS, A fragments persist in registers).
// ---------------------------------------------------------------------------
struct PCArgs {
    const int* edst[4];
    int ebase[5];
    int nbase[4];
    int* deg;
    int cblk;
    const float* A[6];
    int N[6];
    int blk0[7];
    const unsigned short* Wt1[6];
    const unsigned short* cb1[6];
    unsigned short* hs1[6];
    float* el1[6];
    float* er1[6];
    const unsigned short* Wt2[6];
    const unsigned short* cb2[6];
    unsigned short* hs2[6];
    float* el2[6];
    float* er2[6];
    int has2[6];
};

__global__ __launch_bounds__(256) void project_count(PCArgs a) {
    __shared__ unsigned short Abf[64 * 128];   // 16 KiB
    __shared__ unsigned short Wl[144 * 128];   // 36 KiB
    int bb = blockIdx.x;
    const int tid = threadIdx.x;
    if (bb < a.cblk) {
        int idx = bb * 256 + tid;
        if (idx < a.ebase[4]) {
            int r = 0;
            while (idx >= a.ebase[r + 1]) ++r;
            atomicAdd(&a.deg[a.nbase[r] + a.edst[r][idx - a.ebase[r]]], 1);
        }
        return;
    }
    bb -= a.cblk;
    int t = 0;
    while (bb >= a.blk0[t + 1]) ++t;
    const int row0 = (bb - a.blk0[t]) * 64;
    const int N = a.N[t];
    const float* A = a.A[t];

    // stage A (f32 -> bf16, swizzled)
#pragma unroll
    for (int it = 0; it < 4; ++it) {
        int id = it * 256 + tid;
        int r = id >> 4, c8 = id & 15;
        int row = row0 + r;
        if (row >= N) row = N - 1;
        const float4* ap = reinterpret_cast<const float4*>(A + (size_t)row * 128 + c8 * 8);
        float4 v0 = ap[0], v1 = ap[1];
        uint4 pk;
        pk.x = (unsigned)f2bf(v0.x) | ((unsigned)f2bf(v0.y) << 16);
        pk.y = (unsigned)f2bf(v0.z) | ((unsigned)f2bf(v0.w) << 16);
        pk.z = (unsigned)f2bf(v1.x) | ((unsigned)f2bf(v1.y) << 16);
        pk.w = (unsigned)f2bf(v1.z) | ((unsigned)f2bf(v1.w) << 16);
        *reinterpret_cast<uint4*>(&Abf[(r * 16 + (c8 ^ (r & 15))) * 8]) = pk;
    }
    stage_W(Wl, a.Wt1[t], a.cb1[t], tid);
    __syncthreads();

    // hoist A fragments (wave w owns rows w*16..w*16+15)
    const int l = tid & 63, w = tid >> 6, lrow = l & 15, lk8 = l >> 4;
    bf16x8 af[4];
    const int arow = w * 16 + lrow;
#pragma unroll
    for (int ks = 0; ks < 4; ++ks) {
        int c8 = ks * 4 + lk8;
        af[ks] = *reinterpret_cast<const bf16x8*>(
            &Abf[(arow * 16 + (c8 ^ (arow & 15))) * 8]);
    }
    __syncthreads();  // Abf now reusable as output staging

    mfma_set(Wl, Abf, af, tid, row0, N, a.el1[t], a.er1[t]);
    __syncthreads();
    store_hs(Abf, a.hs1[t], tid, row0, N);
    if (!a.has2[t]) return;
    stage_W(Wl, a.Wt2[t], a.cb2[t], tid);
    __syncthreads();
    mfma_set(Wl, Abf, af, tid, row0, N, a.el2[t], a.er2[t]);
    __syncthreads();
    store_hs(Abf, a.hs2[t], tid, row0, N);
}

// ---------------------------------------------------------------------------
// scan: per-1024-chunk sums, then final scan (computes own bsums prefix)
// ---------------------------------------------------------------------------
__global__ __launch_bounds__(256) void scan_bsum(const int* __restrict__ deg,
                                                 int* __restrict__ bsums, int N) {
    int base = blockIdx.x * 1024 + threadIdx.x * 4;
    int s = 0;
#pragma unroll
    for (int j = 0; j < 4; ++j) {
        int i = base + j;
        if (i < N) s += deg[i];
    }
#pragma unroll
    for (int off = 32; off; off >>= 1) s += __shfl_down(s, off);
    __shared__ int wt[4];
    if ((threadIdx.x & 63) == 0) wt[threadIdx.x >> 6] = s;
    __syncthreads();
    if (threadIdx.x == 0) bsums[blockIdx.x] = wt[0] + wt[1] + wt[2] + wt[3];
}

__global__ __launch_bounds__(256) void scan_final(const int* __restrict__ deg,
                                                  const int* __restrict__ bsums,
                                                  int* __restrict__ row_ptr,
                                                  int* __restrict__ cursor, int N) {
    int t = threadIdx.x;
    // exclusive prefix of bsums over [0, blockIdx.x)
    __shared__ int s_start;
    __shared__ int wsum[4];
    {
        int acc = 0;
        for (int i = t; i < (int)blockIdx.x; i += 256) acc += bsums[i];
#pragma unroll
        for (int off = 32; off; off >>= 1) acc += __shfl_down(acc, off);
        if ((t & 63) == 0) wsum[t >> 6] = acc;
        __syncthreads();
        if (t == 0) s_start = wsum[0] + wsum[1] + wsum[2] + wsum[3];
        __syncthreads();
    }
    int base = blockIdx.x * 1024 + t * 4;
    int d[4];
    int s = 0;
#pragma unroll
    for (int j = 0; j < 4; ++j) {
        int i = base + j;
        d[j] = (i < N) ? deg[i] : 0;
        s += d[j];
    }
    int inc = s;
#pragma unroll
    for (int off = 1; off < 64; off <<= 1) {
        int u = __shfl_up(inc, off);
        if ((t & 63) >= off) inc += u;
    }
    __shared__ int wt[4];
    if ((t & 63) == 63) wt[t >> 6] = inc;
    __syncthreads();
    int start = s_start;
    for (int w = 0; w < (t >> 6); ++w) start += wt[w];
    start += inc - s;
#pragma unroll
    for (int j = 0; j < 4; ++j) {
        int i = base + j;
        if (i < N) {
            row_ptr[i] = start;
            cursor[i] = start;
        }
        start += d[j];
    }
    if (base < N && base + 4 >= N) row_ptr[N] = start;
}

struct CsrPtrs {
    const int* esrc[4];
    const int* edst[4];
    int ebase[5];
    int nbase[4];
};

__global__ void csr_scatter(CsrPtrs cp, int* __restrict__ cursor,
                            int* __restrict__ srcs) {
    int idx = blockIdx.x * 256 + threadIdx.x;
    if (idx >= cp.ebase[4]) return;
    int r = 0;
    while (idx >= cp.ebase[r + 1]) ++r;
    int e = idx - cp.ebase[r];
    int p = atomicAdd(&cursor[cp.nbase[r] + cp.edst[r][e]], 1);
    srcs[p] = cp.esrc[r][e];
}

// ---------------------------------------------------------------------------
// edge-list accumulate (16-lane group, 4-edge unroll)
// ---------------------------------------------------------------------------
__device__ __forceinline__ void acc_list(int p0, int p1, float erd, int l, int h,
                                         const int* __restrict__ srcs,
                                         const float* __restrict__ el,
                                         const unsigned short* __restrict__ hs,
                                         float* A, float& DS) {
    float a4[4][8];
    float dv[4] = {0.f, 0.f, 0.f, 0.f};
#pragma unroll
    for (int u = 0; u < 4; ++u)
#pragma unroll
        for (int j = 0; j < 8; ++j) a4[u][j] = 0.f;
    int p = p0;
    for (; p + 4 <= p1; p += 4) {
        int sx[4];
#pragma unroll
        for (int u = 0; u < 4; ++u) sx[u] = srcs[p + u];
        float ev[4];
        uint4 q[4];
#pragma unroll
        for (int u = 0; u < 4; ++u) {
            ev[u] = el[(size_t)sx[u] * 8 + h] + erd;
            q[u] = *reinterpret_cast<const uint4*>(hs + (size_t)sx[u] * 128 + l * 8);
        }
#pragma unroll
        for (int u = 0; u < 4; ++u) {
            float e = ev[u];
            e = e > 0.f ? e : 0.2f * e;
            float ee = __expf(e);
            dv[u] += ee;
            a4[u][0] += ee * bf2f_lo(q[u].x);
            a4[u][1] += ee * bf2f_hi(q[u].x);
            a4[u][2] += ee * bf2f_lo(q[u].y);
            a4[u][3] += ee * bf2f_hi(q[u].y);
            a4[u][4] += ee * bf2f_lo(q[u].z);
            a4[u][5] += ee * bf2f_hi(q[u].z);
            a4[u][6] += ee * bf2f_lo(q[u].w);
            a4[u][7] += ee * bf2f_hi(q[u].w);
        }
    }
    for (; p < p1; ++p) {
        int s = srcs[p];
        float e = el[(size_t)s * 8 + h] + erd;
        e = e > 0.f ? e : 0.2f * e;
        float ee = __expf(e);
        uint4 q = *reinterpret_cast<const uint4*>(hs + (size_t)s * 128 + l * 8);
        dv[0] += ee;
        a4[0][0] += ee * bf2f_lo(q.x);
        a4[0][1] += ee * bf2f_hi(q.x);
        a4[0][2] += ee * bf2f_lo(q.y);
        a4[0][3] += ee * bf2f_hi(q.y);
        a4[0][4] += ee * bf2f_lo(q.z);
        a4[0][5] += ee * bf2f_hi(q.z);
        a4[0][6] += ee * bf2f_lo(q.w);
        a4[0][7] += ee * bf2f_hi(q.w);
    }
#pragma unroll
    for (int j = 0; j < 8; ++j) A[j] = a4[0][j] + a4[1][j] + a4[2][j] + a4[3][j];
    DS = dv[0] + dv[1] + dv[2] + dv[3];
}

// ---------------------------------------------------------------------------
// Mega aggregation: one dispatch, block ranges:
//   [0, 12500): paper (rel1+rel3 fused), both inputs
//   [12500, 20000): author (rel0), both inputs
//   [20000, 22000): subject (rel2), one block per (input,dst)
// ---------------------------------------------------------------------------
#define PB 12500
#define AB 7500
#define SB 2000

struct AggArgs {
    const int* rp;
    const int* srcs;
    const float* el[8];              // [inp*4 + rel]
    const float* er[8];
    const unsigned short* hs[8];
    const float* bs;                 // 4 x 128
    float* out0;
    float* out1;
};

__global__ __launch_bounds__(256) void mega_agg(AggArgs a) {
    int blk = blockIdx.x;
    __shared__ float Am[16][128];
    __shared__ float Dm[16][8];

    if (blk < PB) {
        // ---- paper region: rel1 (author->paper) + rel3 (subject->paper) ----
        int g = blk * 16 + (threadIdx.x >> 4);
        int l = threadIdx.x & 15, h = l >> 1;
        int inp = g >= NPAPER;
        int dst = inp ? g - NPAPER : g;
        float* out = (inp ? a.out1 : a.out0) + (size_t)dst * 128 + l * 8;
        float A1[8], A3[8], d1, d3;
        acc_list(a.rp[60000 + dst], a.rp[60000 + dst + 1],
                 a.er[inp * 4 + 1][(size_t)dst * 8 + h], l, h, a.srcs,
                 a.el[inp * 4 + 1], a.hs[inp * 4 + 1], A1, d1);
        acc_list(a.rp[161000 + dst], a.rp[161000 + dst + 1],
                 a.er[inp * 4 + 3][(size_t)dst * 8 + h], l, h, a.srcs,
                 a.el[inp * 4 + 3], a.hs[inp * 4 + 3], A3, d3);
        float i1 = 1.f / fmaxf(d1, 1e-9f);
        float i3 = 1.f / fmaxf(d3, 1e-9f);
        const float4* bp1 = reinterpret_cast<const float4*>(a.bs + 128 + l * 8);
        const float4* bp3 = reinterpret_cast<const float4*>(a.bs + 384 + l * 8);
        float4 b10 = bp1[0], b11 = bp1[1], b30 = bp3[0], b31 = bp3[1];
        float4 o0, o1;
        o0.x = 0.5f * ((A1[0] * i1 + b10.x) + (A3[0] * i3 + b30.x));
        o0.y = 0.5f * ((A1[1] * i1 + b10.y) + (A3[1] * i3 + b30.y));
        o0.z = 0.5f * ((A1[2] * i1 + b10.z) + (A3[2] * i3 + b30.z));
        o0.w = 0.5f * ((A1[3] * i1 + b10.w) + (A3[3] * i3 + b30.w));
        o1.x = 0.5f * ((A1[4] * i1 + b11.x) + (A3[4] * i3 + b31.x));
        o1.y = 0.5f * ((A1[5] * i1 + b11.y) + (A3[5] * i3 + b31.y));
        o1.z = 0.5f * ((A1[6] * i1 + b11.z) + (A3[6] * i3 + b31.z));
        o1.w = 0.5f * ((A1[7] * i1 + b11.w) + (A3[7] * i3 + b31.w));
        reinterpret_cast<float4*>(out)[0] = o0;
        reinterpret_cast<float4*>(out)[1] = o1;
    } else if (blk < PB + AB) {
        // ---- author region: rel0 (paper->author) ----
        int g = (blk - PB) * 16 + (threadIdx.x >> 4);
        int l = threadIdx.x & 15, h = l >> 1;
        int inp = g >= NAUTHOR;
        int dst = inp ? g - NAUTHOR : g;
        float* out = (inp ? a.out1 : a.out0) + (size_t)(NPAPER + dst) * 128 + l * 8;
        float A[8], ds;
        acc_list(a.rp[dst], a.rp[dst + 1], a.er[inp * 4 + 0][(size_t)dst * 8 + h], l, h,
                 a.srcs, a.el[inp * 4 + 0], a.hs[inp * 4 + 0], A, ds);
        float inv = 1.f / fmaxf(ds, 1e-9f);
        const float4* bp = reinterpret_cast<const float4*>(a.bs + l * 8);
        float4 b0 = bp[0], b1 = bp[1];
        float4 o0 = make_float4(A[0] * inv + b0.x, A[1] * inv + b0.y,
                                A[2] * inv + b0.z, A[3] * inv + b0.w);
        float4 o1 = make_float4(A[4] * inv + b1.x, A[5] * inv + b1.y,
                                A[6] * inv + b1.z, A[7] * inv + b1.w);
        reinterpret_cast<float4*>(out)[0] = o0;
        reinterpret_cast<float4*>(out)[1] = o1;
    } else {
        // ---- subject region: rel2 (paper->subject), block per (inp,dst) ----
        int b2 = blk - (PB + AB);
        int inp = b2 >= NSUBJ;
        int dst = inp ? b2 - NSUBJ : b2;
        const float* el = a.el[inp * 4 + 2];
        const float* er = a.er[inp * 4 + 2];
        const unsigned short* hs = a.hs[inp * 4 + 2];
        float* out = (inp ? a.out1 : a.out0) + (size_t)(NPAPER + NAUTHOR + dst) * 128;
        int gl = threadIdx.x >> 4;
        int l = threadIdx.x & 15, h = l >> 1;
        int p0 = a.rp[160000 + dst], p1 = a.rp[160000 + dst + 1];
        float erd = er[(size_t)dst * 8 + h];
        float acc8[8];
#pragma unroll
        for (int j = 0; j < 8; ++j) acc8[j] = 0.f;
        float dsum = 0.f;
        for (int p = p0 + gl; p < p1; p += 16) {
            int s = a.srcs[p];
            float e = el[(size_t)s * 8 + h] + erd;
            e = e > 0.f ? e : 0.2f * e;
            float ee = __expf(e);
            uint4 q = *reinterpret_cast<const uint4*>(hs + (size_t)s * 128 + l * 8);
            dsum += ee;
            acc8[0] += ee * bf2f_lo(q.x);
            acc8[1] += ee * bf2f_hi(q.x);
            acc8[2] += ee * bf2f_lo(q.y);
            acc8[3] += ee * bf2f_hi(q.y);
            acc8[4] += ee * bf2f_lo(q.z);
            acc8[5] += ee * bf2f_hi(q.z);
            acc8[6] += ee * bf2f_lo(q.w);
            acc8[7] += ee * bf2f_hi(q.w);
        }
#pragma unroll
        for (int j = 0; j < 8; ++j) Am[gl][l * 8 + j] = acc8[j];
        if ((l & 1) == 0) Dm[gl][h] = dsum;
        __syncthreads();
        int c = threadIdx.x;
        if (c < 128) {
            float s = 0.f, dn = 0.f;
            int hh = c >> 4;
#pragma unroll
            for (int g = 0; g < 16; ++g) {
                s += Am[g][c];
                dn += Dm[g][hh];
            }
            out[c] = s / fmaxf(dn, 1e-9f) + a.bs[256 + c];
        }
    }
}

// ---------------------------------------------------------------------------
extern "C" void kernel_launch(void* const* d_in, const int* in_sizes, int n_in,
                              void* d_out, int out_size, void* d_ws, size_t ws_size,
                              hipStream_t stream) {
    const float* Ws4 = (const float*)d_in[14];
    const float* als = (const float*)d_in[15];
    const float* ars = (const float*)d_in[16];
    const float* bs = (const float*)d_in[17];
    float* out = (float*)d_out;

    const int Es[4] = {in_sizes[6], in_sizes[8], in_sizes[10], in_sizes[12]};
    const int Nsrcs[4] = {NPAPER, NAUTHOR, NPAPER, NSUBJ};
    const int Ndsts[4] = {NAUTHOR, NPAPER, NSUBJ, NPAPER};
    const int Etot = Es[0] + Es[1] + Es[2] + Es[3];

    char* wsp = (char*)d_ws;
    auto carve = [&](size_t bytes) {
        char* p = wsp;
        wsp += (bytes + 255) & ~(size_t)255;
        return p;
    };
    unsigned short* Wt = (unsigned short*)carve(4 * 16384 * 2);
    unsigned short* combo = (unsigned short*)carve(4 * 2048 * 2);
    unsigned short* hsb[2][4];
    float* elb[2][4];
    float* erb[2][4];
    for (int i = 0; i < 2; ++i)
        for (int r = 0; r < 4; ++r) {
            hsb[i][r] = (unsigned short*)carve((size_t)Nsrcs[r] * 128 * 2);
            elb[i][r] = (float*)carve((size_t)Nsrcs[r] * 8 * 4);
            erb[i][r] = (float*)carve((size_t)Ndsts[r] * 8 * 4);
        }
    int* deg = (int*)carve((size_t)NDEG * 4);
    int* cursor = (int*)carve((size_t)NDEG * 4);
    int* bsums = (int*)carve(1024);
    int* rp = (int*)carve((size_t)(NDEG + 1) * 4);
    int* scsr = (int*)carve((size_t)Etot * 4);

    // 1. prep (Wt/combo) + deg zero
    prep_kernel<<<288 + (NDEG + 1023) / 1024, 256, 0, stream>>>(Ws4, als, ars, Wt,
                                                                combo, deg);

    // 2. project + csr count (count blocks first)
    PCArgs pc;
    pc.edst[0] = (const int*)d_in[7];
    pc.edst[1] = (const int*)d_in[9];
    pc.edst[2] = (const int*)d_in[11];
    pc.edst[3] = (const int*)d_in[13];
    pc.ebase[0] = 0;
    for (int r = 0; r < 4; ++r) pc.ebase[r + 1] = pc.ebase[r] + Es[r];
    pc.nbase[0] = 0;
    pc.nbase[1] = 60000;
    pc.nbase[2] = 160000;
    pc.nbase[3] = 161000;
    pc.deg = deg;
    pc.cblk = (Etot + 255) / 256;

    // tasks: 0/1 paper inp0/inp1 (W0 + W2), 2/3 author (W1), 4/5 subject (W3)
    int blk = 0;
    for (int ti = 0; ti < 6; ++ti) {
        int i = ti & 1;
        int nodeT = ti >> 1;  // 0 paper, 1 author, 2 subject
        const int relOf[3] = {0, 1, 3};
        int r = relOf[nodeT];
        const float* feats[3] = {(const float*)d_in[0 + 3 * i],
                                 (const float*)d_in[1 + 3 * i],
                                 (const float*)d_in[2 + 3 * i]};
        pc.A[ti] = feats[nodeT];
        pc.N[ti] = (nodeT == 0) ? NPAPER : (nodeT == 1 ? NAUTHOR : NSUBJ);
        pc.blk0[ti] = blk;
        blk += (pc.N[ti] + 63) / 64;
        pc.Wt1[ti] = Wt + (size_t)r * 16384;
        pc.cb1[ti] = combo + (size_t)r * 2048;
        pc.hs1[ti] = hsb[i][r];
        pc.el1[ti] = elb[i][r];
        pc.er1[ti] = erb[i][r ^ 1];
        pc.has2[ti] = (nodeT == 0);
        int r2 = 2;  // paper second set = rel2
        pc.Wt2[ti] = Wt + (size_t)r2 * 16384;
        pc.cb2[ti] = combo + (size_t)r2 * 2048;
        pc.hs2[ti] = hsb[i][r2];
        pc.el2[ti] = elb[i][r2];
        pc.er2[ti] = erb[i][r2 ^ 1];
    }
    pc.blk0[6] = blk;
    project_count<<<pc.cblk + blk, 256, 0, stream>>>(pc);

    // 3-4. scan
    int nb = (NDEG + 1023) / 1024;  // 255
    scan_bsum<<<nb, 256, 0, stream>>>(deg, bsums, NDEG);
    scan_final<<<nb, 256, 0, stream>>>(deg, bsums, rp, cursor, NDEG);

    // 5. scatter
    CsrPtrs cp;
    cp.esrc[0] = (const int*)d_in[6];  cp.edst[0] = (const int*)d_in[7];
    cp.esrc[1] = (const int*)d_in[8];  cp.edst[1] = (const int*)d_in[9];
    cp.esrc[2] = (const int*)d_in[10]; cp.edst[2] = (const int*)d_in[11];
    cp.esrc[3] = (const int*)d_in[12]; cp.edst[3] = (const int*)d_in[13];
    for (int r = 0; r < 5; ++r) cp.ebase[r] = pc.ebase[r];
    for (int r = 0; r < 4; ++r) cp.nbase[r] = pc.nbase[r];
    csr_scatter<<<(Etot + 255) / 256, 256, 0, stream>>>(cp, cursor, scsr);

    // 6. mega aggregation
    AggArgs ag;
    ag.rp = rp;
    ag.srcs = scsr;
    for (int i = 0; i < 2; ++i)
        for (int r = 0; r < 4; ++r) {
            ag.el[i * 4 + r] = elb[i][r];
            ag.er[i * 4 + r] = erb[i][r];
            ag.hs[i * 4 + r] = hsb[i][r];
        }
    ag.bs = bs;
    ag.out0 = out;
    ag.out1 = out + (size_t)NTOT * 128;
    mega_agg<<<PB + AB + SB, 256, 0, stream>>>(ag);
}

// Round 8
// 324.505 us; speedup vs baseline: 11.9211x; 1.1834x over previous
//
#include <hip/hip_runtime.h>

#define NHEAD 8
#define NPAPER 100000
#define NAUTHOR 60000
#define NSUBJ 1000
#define NTOT (NPAPER + NAUTHOR + NSUBJ)
#define NDEG 261000  // author(60000) + paper(100000) + subject(1000) + paper(100000)

typedef __attribute__((ext_vector_type(8))) short bf16x8;
typedef __attribute__((ext_vector_type(4))) float f32x4;
typedef __attribute__((ext_vector_type(4))) unsigned int u32x4;

__device__ __forceinline__ unsigned short f2bf(float x) {
    unsigned int u = __builtin_bit_cast(unsigned int, x);
    u += 0x7fffu + ((u >> 16) & 1u);
    return (unsigned short)(u >> 16);
}
__device__ __forceinline__ float bf2f_lo(unsigned int v) {
    return __builtin_bit_cast(float, v << 16);
}
__device__ __forceinline__ float bf2f_hi(unsigned int v) {
    return __builtin_bit_cast(float, v & 0xffff0000u);
}

// ---------------------------------------------------------------------------
// prep (+ deg zero): Wt[r][c][k] = bf16(W[r][k][c]); combo[r][n][k]:
// n<8 el-reduce (als[r]), n>=8 er-reduce of partner rel (ars[r^1]).
// ---------------------------------------------------------------------------
__global__ void prep_kernel(const float* __restrict__ Ws, const float* __restrict__ als,
                            const float* __restrict__ ars,
                            unsigned short* __restrict__ Wt,
                            unsigned short* __restrict__ combo, int* __restrict__ deg) {
    int b = blockIdx.x;
    if (b >= 288) {
        int idx = (b - 288) * 1024 + threadIdx.x * 4;
        if (idx < NDEG) *reinterpret_cast<int4*>(&deg[idx]) = int4{0, 0, 0, 0};
        return;
    }
    int idx = b * 256 + threadIdx.x;
    if (idx < 65536) {
        int r = idx >> 14, rem = idx & 16383, c = rem >> 7, k = rem & 127;
        Wt[idx] = f2bf(Ws[(r << 14) + k * 128 + c]);
    } else if (idx < 65536 + 8192) {
        int j = idx - 65536;
        int r = j >> 11, rem = j & 2047, n = rem >> 7, k = rem & 127;
        int p = r ^ 1;
        const float *W, *a;
        if (n < 8) {
            W = Ws + (r << 14) + k * 128 + n * 16;
            a = als + r * 128 + n * 16;
        } else {
            int h = n - 8;
            W = Ws + (p << 14) + k * 128 + h * 16;
            a = ars + p * 128 + h * 16;
        }
        float s = 0.f;
#pragma unroll
        for (int d = 0; d < 16; ++d) s += W[d] * a[d];
        combo[j] = f2bf(s);
    }
}

// ---------------------------------------------------------------------------
// Projection helpers
// ---------------------------------------------------------------------------
__device__ __forceinline__ void stage_W(unsigned short* Wl, const unsigned short* Wt,
                                        const unsigned short* cb, int tid) {
#pragma unroll
    for (int it = 0; it < 9; ++it) {
        int id = it * 256 + tid;
        int r = id >> 4, c8 = id & 15;
        const unsigned short* srcp = (r < 128) ? (Wt + r * 128) : (cb + (r - 128) * 128);
        uint4 v = *reinterpret_cast<const uint4*>(srcp + c8 * 8);
        *reinterpret_cast<uint4*>(&Wl[(r * 16 + (c8 ^ (r & 15))) * 8]) = v;
    }
}

__device__ __forceinline__ void mfma_set(const unsigned short* Wl, unsigned short* Abf,
                                         const bf16x8* af, int tid, int row0, int N,
                                         float* __restrict__ el, float* __restrict__ er) {
    const int l = tid & 63, w = tid >> 6, lrow = l & 15, lk8 = l >> 4;
#pragma unroll
    for (int t9 = 0; t9 < 9; ++t9) {
        f32x4 acc = f32x4{0.f, 0.f, 0.f, 0.f};
#pragma unroll
        for (int ks = 0; ks < 4; ++ks) {
            int wrow = t9 * 16 + lrow;
            int c8 = ks * 4 + lk8;
            bf16x8 bf = *reinterpret_cast<const bf16x8*>(
                &Wl[(wrow * 16 + (c8 ^ (wrow & 15))) * 8]);
            acc = __builtin_amdgcn_mfma_f32_16x16x32_bf16(af[ks], bf, acc, 0, 0, 0);
        }
        if (t9 < 8) {
#pragma unroll
            for (int r = 0; r < 4; ++r) {
                int rl = w * 16 + lk8 * 4 + r;
                int col = t9 * 16 + lrow;
                Abf[(rl * 16 + ((col >> 3) ^ (rl & 15))) * 8 + (col & 7)] = f2bf(acc[r]);
            }
        } else {
#pragma unroll
            for (int r = 0; r < 4; ++r) {
                int row = row0 + w * 16 + lk8 * 4 + r;
                if (row < N) {
                    if (lrow < 8) el[(size_t)row * 8 + lrow] = acc[r];
                    else er[(size_t)row * 8 + (lrow - 8)] = acc[r];
                }
            }
        }
    }
}

__device__ __forceinline__ void store_hs(const unsigned short* Abf,
                                         unsigned short* __restrict__ hs, int tid,
                                         int row0, int N) {
#pragma unroll
    for (int it = 0; it < 4; ++it) {
        int id = it * 256 + tid;
        int r = id >> 4, c8 = id & 15;
        int row = row0 + r;
        if (row < N) {
            uint4 v = *reinterpret_cast<const uint4*>(&Abf[(r * 16 + (c8 ^ (r & 15))) * 8]);
            *reinterpret_cast<uint4*>(hs + (size_t)row * 128 + c8 * 8) = v;
        }
    }
}

// ---------------------------------------------------------------------------
// Fused projection + CSR count.
// ---------------------------------------------------------------------------
struct PCArgs {
    const int* edst[4];
    int ebase[5];
    int nbase[4];
    int* deg;
    int cblk;
    const float* A[6];
    int N[6];
    int blk0[7];
    const unsigned short* Wt1[6];
    const unsigned short* cb1[6];
    unsigned short* hs1[6];
    float* el1[6];
    float* er1[6];
    const unsigned short* Wt2[6];
    const unsigned short* cb2[6];
    unsigned short* hs2[6];
    float* el2[6];
    float* er2[6];
    int has2[6];
};

__global__ __launch_bounds__(256) void project_count(PCArgs a) {
    __shared__ unsigned short Abf[64 * 128];   // 16 KiB
    __shared__ unsigned short Wl[144 * 128];   // 36 KiB
    int bb = blockIdx.x;
    const int tid = threadIdx.x;
    if (bb < a.cblk) {
        int idx = bb * 256 + tid;
        if (idx < a.ebase[4]) {
            int r = 0;
            while (idx >= a.ebase[r + 1]) ++r;
            atomicAdd(&a.deg[a.nbase[r] + a.edst[r][idx - a.ebase[r]]], 1);
        }
        return;
    }
    bb -= a.cblk;
    int t = 0;
    while (bb >= a.blk0[t + 1]) ++t;
    const int row0 = (bb - a.blk0[t]) * 64;
    const int N = a.N[t];
    const float* A = a.A[t];

    // stage A (f32 -> bf16, swizzled); nontemporal: features are read-once
#pragma unroll
    for (int it = 0; it < 4; ++it) {
        int id = it * 256 + tid;
        int r = id >> 4, c8 = id & 15;
        int row = row0 + r;
        if (row >= N) row = N - 1;
        const f32x4* ap = reinterpret_cast<const f32x4*>(A + (size_t)row * 128 + c8 * 8);
        f32x4 v0 = __builtin_nontemporal_load(ap);
        f32x4 v1 = __builtin_nontemporal_load(ap + 1);
        uint4 pk;
        pk.x = (unsigned)f2bf(v0.x) | ((unsigned)f2bf(v0.y) << 16);
        pk.y = (unsigned)f2bf(v0.z) | ((unsigned)f2bf(v0.w) << 16);
        pk.z = (unsigned)f2bf(v1.x) | ((unsigned)f2bf(v1.y) << 16);
        pk.w = (unsigned)f2bf(v1.z) | ((unsigned)f2bf(v1.w) << 16);
        *reinterpret_cast<uint4*>(&Abf[(r * 16 + (c8 ^ (r & 15))) * 8]) = pk;
    }
    stage_W(Wl, a.Wt1[t], a.cb1[t], tid);
    __syncthreads();

    const int l = tid & 63, w = tid >> 6, lrow = l & 15, lk8 = l >> 4;
    bf16x8 af[4];
    const int arow = w * 16 + lrow;
#pragma unroll
    for (int ks = 0; ks < 4; ++ks) {
        int c8 = ks * 4 + lk8;
        af[ks] = *reinterpret_cast<const bf16x8*>(
            &Abf[(arow * 16 + (c8 ^ (arow & 15))) * 8]);
    }
    __syncthreads();  // Abf now reusable as output staging

    mfma_set(Wl, Abf, af, tid, row0, N, a.el1[t], a.er1[t]);
    __syncthreads();
    store_hs(Abf, a.hs1[t], tid, row0, N);
    if (!a.has2[t]) return;
    stage_W(Wl, a.Wt2[t], a.cb2[t], tid);
    __syncthreads();
    mfma_set(Wl, Abf, af, tid, row0, N, a.el2[t], a.er2[t]);
    __syncthreads();
    store_hs(Abf, a.hs2[t], tid, row0, N);
}

// ---------------------------------------------------------------------------
// scan
// ---------------------------------------------------------------------------
__global__ __launch_bounds__(256) void scan_bsum(const int* __restrict__ deg,
                                                 int* __restrict__ bsums, int N) {
    int base = blockIdx.x * 1024 + threadIdx.x * 4;
    int s = 0;
#pragma unroll
    for (int j = 0; j < 4; ++j) {
        int i = base + j;
        if (i < N) s += deg[i];
    }
#pragma unroll
    for (int off = 32; off; off >>= 1) s += __shfl_down(s, off);
    __shared__ int wt[4];
    if ((threadIdx.x & 63) == 0) wt[threadIdx.x >> 6] = s;
    __syncthreads();
    if (threadIdx.x == 0) bsums[blockIdx.x] = wt[0] + wt[1] + wt[2] + wt[3];
}

__global__ __launch_bounds__(256) void scan_final(const int* __restrict__ deg,
                                                  const int* __restrict__ bsums,
                                                  int* __restrict__ row_ptr,
                                                  int* __restrict__ cursor, int N) {
    int t = threadIdx.x;
    __shared__ int s_start;
    __shared__ int wsum[4];
    {
        int acc = 0;
        for (int i = t; i < (int)blockIdx.x; i += 256) acc += bsums[i];
#pragma unroll
        for (int off = 32; off; off >>= 1) acc += __shfl_down(acc, off);
        if ((t & 63) == 0) wsum[t >> 6] = acc;
        __syncthreads();
        if (t == 0) s_start = wsum[0] + wsum[1] + wsum[2] + wsum[3];
        __syncthreads();
    }
    int base = blockIdx.x * 1024 + t * 4;
    int d[4];
    int s = 0;
#pragma unroll
    for (int j = 0; j < 4; ++j) {
        int i = base + j;
        d[j] = (i < N) ? deg[i] : 0;
        s += d[j];
    }
    int inc = s;
#pragma unroll
    for (int off = 1; off < 64; off <<= 1) {
        int u = __shfl_up(inc, off);
        if ((t & 63) >= off) inc += u;
    }
    __shared__ int wt[4];
    if ((t & 63) == 63) wt[t >> 6] = inc;
    __syncthreads();
    int start = s_start;
    for (int w = 0; w < (t >> 6); ++w) start += wt[w];
    start += inc - s;
#pragma unroll
    for (int j = 0; j < 4; ++j) {
        int i = base + j;
        if (i < N) {
            row_ptr[i] = start;
            cursor[i] = start;
        }
        start += d[j];
    }
    if (base < N && base + 4 >= N) row_ptr[N] = start;
}

struct CsrPtrs {
    const int* esrc[4];
    const int* edst[4];
    int ebase[5];
    int nbase[4];
};

__global__ void csr_scatter(CsrPtrs cp, int* __restrict__ cursor,
                            int* __restrict__ srcs) {
    int idx = blockIdx.x * 256 + threadIdx.x;
    if (idx >= cp.ebase[4]) return;
    int r = 0;
    while (idx >= cp.ebase[r + 1]) ++r;
    int e = idx - cp.ebase[r];
    int p = atomicAdd(&cursor[cp.nbase[r] + cp.edst[r][e]], 1);
    srcs[p] = cp.esrc[r][e];
}

// ---------------------------------------------------------------------------
// Dual-input edge-list accumulate: both inputs share srcs; 16 independent
// loads in flight per 4-edge step.
// ---------------------------------------------------------------------------
__device__ __forceinline__ void acc_dual(
    int p0, int p1, float erd0, float erd1, int l, int h,
    const int* __restrict__ srcs,
    const float* __restrict__ el0, const float* __restrict__ el1,
    const unsigned short* __restrict__ hs0, const unsigned short* __restrict__ hs1,
    float* A0, float* A1, float& DS0, float& DS1) {
    float a0[8], a1[8];
#pragma unroll
    for (int j = 0; j < 8; ++j) { a0[j] = 0.f; a1[j] = 0.f; }
    float d0 = 0.f, d1 = 0.f;
    int p = p0;
    for (; p + 4 <= p1; p += 4) {
        int sx[4];
#pragma unroll
        for (int u = 0; u < 4; ++u) sx[u] = srcs[p + u];
        float ev0[4], ev1[4];
        uint4 q0[4], q1[4];
#pragma unroll
        for (int u = 0; u < 4; ++u) {
            ev0[u] = el0[(size_t)sx[u] * 8 + h] + erd0;
            ev1[u] = el1[(size_t)sx[u] * 8 + h] + erd1;
            q0[u] = *reinterpret_cast<const uint4*>(hs0 + (size_t)sx[u] * 128 + l * 8);
            q1[u] = *reinterpret_cast<const uint4*>(hs1 + (size_t)sx[u] * 128 + l * 8);
        }
#pragma unroll
        for (int u = 0; u < 4; ++u) {
            float e0 = ev0[u];
            e0 = e0 > 0.f ? e0 : 0.2f * e0;
            float ee0 = __expf(e0);
            d0 += ee0;
            a0[0] += ee0 * bf2f_lo(q0[u].x);
            a0[1] += ee0 * bf2f_hi(q0[u].x);
            a0[2] += ee0 * bf2f_lo(q0[u].y);
            a0[3] += ee0 * bf2f_hi(q0[u].y);
            a0[4] += ee0 * bf2f_lo(q0[u].z);
            a0[5] += ee0 * bf2f_hi(q0[u].z);
            a0[6] += ee0 * bf2f_lo(q0[u].w);
            a0[7] += ee0 * bf2f_hi(q0[u].w);
            float e1 = ev1[u];
            e1 = e1 > 0.f ? e1 : 0.2f * e1;
            float ee1 = __expf(e1);
            d1 += ee1;
            a1[0] += ee1 * bf2f_lo(q1[u].x);
            a1[1] += ee1 * bf2f_hi(q1[u].x);
            a1[2] += ee1 * bf2f_lo(q1[u].y);
            a1[3] += ee1 * bf2f_hi(q1[u].y);
            a1[4] += ee1 * bf2f_lo(q1[u].z);
            a1[5] += ee1 * bf2f_hi(q1[u].z);
            a1[6] += ee1 * bf2f_lo(q1[u].w);
            a1[7] += ee1 * bf2f_hi(q1[u].w);
        }
    }
    for (; p < p1; ++p) {
        int s = srcs[p];
        float e0 = el0[(size_t)s * 8 + h] + erd0;
        float e1 = el1[(size_t)s * 8 + h] + erd1;
        uint4 q0 = *reinterpret_cast<const uint4*>(hs0 + (size_t)s * 128 + l * 8);
        uint4 q1 = *reinterpret_cast<const uint4*>(hs1 + (size_t)s * 128 + l * 8);
        e0 = e0 > 0.f ? e0 : 0.2f * e0;
        float ee0 = __expf(e0);
        d0 += ee0;
        a0[0] += ee0 * bf2f_lo(q0.x);
        a0[1] += ee0 * bf2f_hi(q0.x);
        a0[2] += ee0 * bf2f_lo(q0.y);
        a0[3] += ee0 * bf2f_hi(q0.y);
        a0[4] += ee0 * bf2f_lo(q0.z);
        a0[5] += ee0 * bf2f_hi(q0.z);
        a0[6] += ee0 * bf2f_lo(q0.w);
        a0[7] += ee0 * bf2f_hi(q0.w);
        e1 = e1 > 0.f ? e1 : 0.2f * e1;
        float ee1 = __expf(e1);
        d1 += ee1;
        a1[0] += ee1 * bf2f_lo(q1.x);
        a1[1] += ee1 * bf2f_hi(q1.x);
        a1[2] += ee1 * bf2f_lo(q1.y);
        a1[3] += ee1 * bf2f_hi(q1.y);
        a1[4] += ee1 * bf2f_lo(q1.z);
        a1[5] += ee1 * bf2f_hi(q1.z);
        a1[6] += ee1 * bf2f_lo(q1.w);
        a1[7] += ee1 * bf2f_hi(q1.w);
    }
#pragma unroll
    for (int j = 0; j < 8; ++j) { A0[j] = a0[j]; A1[j] = a1[j]; }
    DS0 = d0;
    DS1 = d1;
}

__device__ __forceinline__ void nt_store2(float* op, f32x4 o0, f32x4 o1) {
    f32x4* vp = reinterpret_cast<f32x4*>(op);
    __builtin_nontemporal_store(o0, vp);
    __builtin_nontemporal_store(o1, vp + 1);
}

// ---------------------------------------------------------------------------
// Mega aggregation, dual-input groups. Block ranges:
//   [0, 6250): paper (rel1+rel3 fused), 16 dsts/block
//   [6250, 10000): author (rel0), 16 dsts/block
//   [10000, 11000): subject (rel2), 1 dst/block, 8 chunks x 2 inputs
// ---------------------------------------------------------------------------
#define PB2 6250
#define AB2 3750
#define SB2 1000

struct AggArgs {
    const int* rp;
    const int* srcs;
    const float* el[8];              // [inp*4 + rel]
    const float* er[8];
    const unsigned short* hs[8];
    const float* bs;                 // 4 x 128
    float* out0;
    float* out1;
};

__global__ __launch_bounds__(256) void mega_agg(AggArgs a) {
    int blk = blockIdx.x;
    __shared__ float Am[16][128];
    __shared__ float Dm[16][8];

    if (blk < PB2) {
        // ---- paper region: rel1 + rel3, both inputs ----
        int dst = blk * 16 + (threadIdx.x >> 4);
        int l = threadIdx.x & 15, h = l >> 1;
        if (dst >= NPAPER) return;
        float A1_0[8], A1_1[8], d1_0, d1_1;
        acc_dual(a.rp[60000 + dst], a.rp[60000 + dst + 1],
                 a.er[1][(size_t)dst * 8 + h], a.er[5][(size_t)dst * 8 + h], l, h,
                 a.srcs, a.el[1], a.el[5], a.hs[1], a.hs[5], A1_0, A1_1, d1_0, d1_1);
        float A3_0[8], A3_1[8], d3_0, d3_1;
        acc_dual(a.rp[161000 + dst], a.rp[161000 + dst + 1],
                 a.er[3][(size_t)dst * 8 + h], a.er[7][(size_t)dst * 8 + h], l, h,
                 a.srcs, a.el[3], a.el[7], a.hs[3], a.hs[7], A3_0, A3_1, d3_0, d3_1);
        const float4* bp1 = reinterpret_cast<const float4*>(a.bs + 128 + l * 8);
        const float4* bp3 = reinterpret_cast<const float4*>(a.bs + 384 + l * 8);
        float4 b10 = bp1[0], b11 = bp1[1], b30 = bp3[0], b31 = bp3[1];
        float i1 = 1.f / fmaxf(d1_0, 1e-9f);
        float i3 = 1.f / fmaxf(d3_0, 1e-9f);
        f32x4 o0, o1;
        o0.x = 0.5f * ((A1_0[0] * i1 + b10.x) + (A3_0[0] * i3 + b30.x));
        o0.y = 0.5f * ((A1_0[1] * i1 + b10.y) + (A3_0[1] * i3 + b30.y));
        o0.z = 0.5f * ((A1_0[2] * i1 + b10.z) + (A3_0[2] * i3 + b30.z));
        o0.w = 0.5f * ((A1_0[3] * i1 + b10.w) + (A3_0[3] * i3 + b30.w));
        o1.x = 0.5f * ((A1_0[4] * i1 + b11.x) + (A3_0[4] * i3 + b31.x));
        o1.y = 0.5f * ((A1_0[5] * i1 + b11.y) + (A3_0[5] * i3 + b31.y));
        o1.z = 0.5f * ((A1_0[6] * i1 + b11.z) + (A3_0[6] * i3 + b31.z));
        o1.w = 0.5f * ((A1_0[7] * i1 + b11.w) + (A3_0[7] * i3 + b31.w));
        nt_store2(a.out0 + (size_t)dst * 128 + l * 8, o0, o1);
        i1 = 1.f / fmaxf(d1_1, 1e-9f);
        i3 = 1.f / fmaxf(d3_1, 1e-9f);
        o0.x = 0.5f * ((A1_1[0] * i1 + b10.x) + (A3_1[0] * i3 + b30.x));
        o0.y = 0.5f * ((A1_1[1] * i1 + b10.y) + (A3_1[1] * i3 + b30.y));
        o0.z = 0.5f * ((A1_1[2] * i1 + b10.z) + (A3_1[2] * i3 + b30.z));
        o0.w = 0.5f * ((A1_1[3] * i1 + b10.w) + (A3_1[3] * i3 + b30.w));
        o1.x = 0.5f * ((A1_1[4] * i1 + b11.x) + (A3_1[4] * i3 + b31.x));
        o1.y = 0.5f * ((A1_1[5] * i1 + b11.y) + (A3_1[5] * i3 + b31.y));
        o1.z = 0.5f * ((A1_1[6] * i1 + b11.z) + (A3_1[6] * i3 + b31.z));
        o1.w = 0.5f * ((A1_1[7] * i1 + b11.w) + (A3_1[7] * i3 + b31.w));
        nt_store2(a.out1 + (size_t)dst * 128 + l * 8, o0, o1);
    } else if (blk < PB2 + AB2) {
        // ---- author region: rel0, both inputs ----
        int dst = (blk - PB2) * 16 + (threadIdx.x >> 4);
        int l = threadIdx.x & 15, h = l >> 1;
        if (dst >= NAUTHOR) return;
        float A0[8], A1[8], d0, d1;
        acc_dual(a.rp[dst], a.rp[dst + 1],
                 a.er[0][(size_t)dst * 8 + h], a.er[4][(size_t)dst * 8 + h], l, h,
                 a.srcs, a.el[0], a.el[4], a.hs[0], a.hs[4], A0, A1, d0, d1);
        const float4* bp = reinterpret_cast<const float4*>(a.bs + l * 8);
        float4 b0 = bp[0], b1 = bp[1];
        float inv = 1.f / fmaxf(d0, 1e-9f);
        f32x4 o0 = {A0[0] * inv + b0.x, A0[1] * inv + b0.y,
                    A0[2] * inv + b0.z, A0[3] * inv + b0.w};
        f32x4 o1 = {A0[4] * inv + b1.x, A0[5] * inv + b1.y,
                    A0[6] * inv + b1.z, A0[7] * inv + b1.w};
        nt_store2(a.out0 + (size_t)(NPAPER + dst) * 128 + l * 8, o0, o1);
        inv = 1.f / fmaxf(d1, 1e-9f);
        o0 = f32x4{A1[0] * inv + b0.x, A1[1] * inv + b0.y,
                   A1[2] * inv + b0.z, A1[3] * inv + b0.w};
        o1 = f32x4{A1[4] * inv + b1.x, A1[5] * inv + b1.y,
                   A1[6] * inv + b1.z, A1[7] * inv + b1.w};
        nt_store2(a.out1 + (size_t)(NPAPER + dst) * 128 + l * 8, o0, o1);
    } else {
        // ---- subject region: rel2; 16 groups = 2 inputs x 8 chunks ----
        int dst = blk - (PB2 + AB2);
        int gl = threadIdx.x >> 4;
        int inp = gl >> 3, ck = gl & 7;
        int l = threadIdx.x & 15, h = l >> 1;
        const float* el = a.el[inp * 4 + 2];
        const float* er = a.er[inp * 4 + 2];
        const unsigned short* hs = a.hs[inp * 4 + 2];
        int p0 = a.rp[160000 + dst], p1 = a.rp[160000 + dst + 1];
        float erd = er[(size_t)dst * 8 + h];
        float acc8[8];
#pragma unroll
        for (int j = 0; j < 8; ++j) acc8[j] = 0.f;
        float dsum = 0.f;
        for (int p = p0 + ck; p < p1; p += 8) {
            int s = a.srcs[p];
            float e = el[(size_t)s * 8 + h] + erd;
            e = e > 0.f ? e : 0.2f * e;
            float ee = __expf(e);
            uint4 q = *reinterpret_cast<const uint4*>(hs + (size_t)s * 128 + l * 8);
            dsum += ee;
            acc8[0] += ee * bf2f_lo(q.x);
            acc8[1] += ee * bf2f_hi(q.x);
            acc8[2] += ee * bf2f_lo(q.y);
            acc8[3] += ee * bf2f_hi(q.y);
            acc8[4] += ee * bf2f_lo(q.z);
            acc8[5] += ee * bf2f_hi(q.z);
            acc8[6] += ee * bf2f_lo(q.w);
            acc8[7] += ee * bf2f_hi(q.w);
        }
#pragma unroll
        for (int j = 0; j < 8; ++j) Am[gl][l * 8 + j] = acc8[j];
        if ((l & 1) == 0) Dm[gl][h] = dsum;
        __syncthreads();
        int c = threadIdx.x;
        int ci = c >> 7;          // input
        int col = c & 127;
        float s = 0.f, dn = 0.f;
        int hh = col >> 4;
#pragma unroll
        for (int g = 0; g < 8; ++g) {
            s += Am[ci * 8 + g][col];
            dn += Dm[ci * 8 + g][hh];
        }
        float v = s / fmaxf(dn, 1e-9f) + a.bs[256 + col];
        float* outp = (ci ? a.out1 : a.out0) + (size_t)(NPAPER + NAUTHOR + dst) * 128 + col;
        __builtin_nontemporal_store(v, outp);
    }
}

// ---------------------------------------------------------------------------
extern "C" void kernel_launch(void* const* d_in, const int* in_sizes, int n_in,
                              void* d_out, int out_size, void* d_ws, size_t ws_size,
                              hipStream_t stream) {
    const float* Ws4 = (const float*)d_in[14];
    const float* als = (const float*)d_in[15];
    const float* ars = (const float*)d_in[16];
    const float* bs = (const float*)d_in[17];
    float* out = (float*)d_out;

    const int Es[4] = {in_sizes[6], in_sizes[8], in_sizes[10], in_sizes[12]};
    const int Nsrcs[4] = {NPAPER, NAUTHOR, NPAPER, NSUBJ};
    const int Ndsts[4] = {NAUTHOR, NPAPER, NSUBJ, NPAPER};
    const int Etot = Es[0] + Es[1] + Es[2] + Es[3];

    char* wsp = (char*)d_ws;
    auto carve = [&](size_t bytes) {
        char* p = wsp;
        wsp += (bytes + 255) & ~(size_t)255;
        return p;
    };
    unsigned short* Wt = (unsigned short*)carve(4 * 16384 * 2);
    unsigned short* combo = (unsigned short*)carve(4 * 2048 * 2);
    unsigned short* hsb[2][4];
    float* elb[2][4];
    float* erb[2][4];
    for (int i = 0; i < 2; ++i)
        for (int r = 0; r < 4; ++r) {
            hsb[i][r] = (unsigned short*)carve((size_t)Nsrcs[r] * 128 * 2);
            elb[i][r] = (float*)carve((size_t)Nsrcs[r] * 8 * 4);
            erb[i][r] = (float*)carve((size_t)Ndsts[r] * 8 * 4);
        }
    int* deg = (int*)carve((size_t)NDEG * 4);
    int* cursor = (int*)carve((size_t)NDEG * 4);
    int* bsums = (int*)carve(1024);
    int* rp = (int*)carve((size_t)(NDEG + 1) * 4);
    int* scsr = (int*)carve((size_t)Etot * 4);

    // 1. prep (Wt/combo) + deg zero
    prep_kernel<<<288 + (NDEG + 1023) / 1024, 256, 0, stream>>>(Ws4, als, ars, Wt,
                                                                combo, deg);

    // 2. project + csr count
    PCArgs pc;
    pc.edst[0] = (const int*)d_in[7];
    pc.edst[1] = (const int*)d_in[9];
    pc.edst[2] = (const int*)d_in[11];
    pc.edst[3] = (const int*)d_in[13];
    pc.ebase[0] = 0;
    for (int r = 0; r < 4; ++r) pc.ebase[r + 1] = pc.ebase[r] + Es[r];
    pc.nbase[0] = 0;
    pc.nbase[1] = 60000;
    pc.nbase[2] = 160000;
    pc.nbase[3] = 161000;
    pc.deg = deg;
    pc.cblk = (Etot + 255) / 256;

    int blk = 0;
    for (int ti = 0; ti < 6; ++ti) {
        int i = ti & 1;
        int nodeT = ti >> 1;  // 0 paper, 1 author, 2 subject
        const int relOf[3] = {0, 1, 3};
        int r = relOf[nodeT];
        const float* feats[3] = {(const float*)d_in[0 + 3 * i],
                                 (const float*)d_in[1 + 3 * i],
                                 (const float*)d_in[2 + 3 * i]};
        pc.A[ti] = feats[nodeT];
        pc.N[ti] = (nodeT == 0) ? NPAPER : (nodeT == 1 ? NAUTHOR : NSUBJ);
        pc.blk0[ti] = blk;
        blk += (pc.N[ti] + 63) / 64;
        pc.Wt1[ti] = Wt + (size_t)r * 16384;
        pc.cb1[ti] = combo + (size_t)r * 2048;
        pc.hs1[ti] = hsb[i][r];
        pc.el1[ti] = elb[i][r];
        pc.er1[ti] = erb[i][r ^ 1];
        pc.has2[ti] = (nodeT == 0);
        int r2 = 2;
        pc.Wt2[ti] = Wt + (size_t)r2 * 16384;
        pc.cb2[ti] = combo + (size_t)r2 * 2048;
        pc.hs2[ti] = hsb[i][r2];
        pc.el2[ti] = elb[i][r2];
        pc.er2[ti] = erb[i][r2 ^ 1];
    }
    pc.blk0[6] = blk;
    project_count<<<pc.cblk + blk, 256, 0, stream>>>(pc);

    // 3-4. scan
    int nb = (NDEG + 1023) / 1024;  // 255
    scan_bsum<<<nb, 256, 0, stream>>>(deg, bsums, NDEG);
    scan_final<<<nb, 256, 0, stream>>>(deg, bsums, rp, cursor, NDEG);

    // 5. scatter
    CsrPtrs cp;
    cp.esrc[0] = (const int*)d_in[6];  cp.edst[0] = (const int*)d_in[7];
    cp.esrc[1] = (const int*)d_in[8];  cp.edst[1] = (const int*)d_in[9];
    cp.esrc[2] = (const int*)d_in[10]; cp.edst[2] = (const int*)d_in[11];
    cp.esrc[3] = (const int*)d_in[12]; cp.edst[3] = (const int*)d_in[13];
    for (int r = 0; r < 5; ++r) cp.ebase[r] = pc.ebase[r];
    for (int r = 0; r < 4; ++r) cp.nbase[r] = pc.nbase[r];
    csr_scatter<<<(Etot + 255) / 256, 256, 0, stream>>>(cp, cursor, scsr);

    // 6. mega aggregation (dual-input groups)
    AggArgs ag;
    ag.rp = rp;
    ag.srcs = scsr;
    for (int i = 0; i < 2; ++i)
        for (int r = 0; r < 4; ++r) {
            ag.el[i * 4 + r] = elb[i][r];
            ag.er[i * 4 + r] = erb[i][r];
            ag.hs[i * 4 + r] = hsb[i][r];
        }
    ag.bs = bs;
    ag.out0 = out;
    ag.out1 = out + (size_t)NTOT * 128;
    mega_agg<<<PB2 + AB2 + SB2, 256, 0, stream>>>(ag);
}